// Round 9
// baseline (584.227 us; speedup 1.0000x reference)
//
#include <hip/hip_runtime.h>
#include <hip/hip_bf16.h>

// GCN link prediction. Inputs fp32+int32; OUTPUT fp32 (scores[1M] ++ embed[n*64]).
// CSR gather + bf16 feature tables (fp32 math), register-tiled 4x4 GEMMs,
// device-wide scan, packed int2 (col,wcol) adjacency (fill was partial-line
// scatter-write bound: 154MB HBM writes for 12.8MB data).

__device__ __forceinline__ float lo16f(uint32_t u) { uint32_t x = u << 16; float f; __builtin_memcpy(&f, &x, 4); return f; }
__device__ __forceinline__ float hi16f(uint32_t u) { uint32_t x = u & 0xffff0000u; float f; __builtin_memcpy(&f, &x, 4); return f; }
__device__ __forceinline__ float u16f(unsigned short u) { uint32_t x = (uint32_t)u << 16; float f; __builtin_memcpy(&f, &x, 4); return f; }
__device__ __forceinline__ uint32_t pk2(float a, float b) {
    union { __hip_bfloat162 h; uint32_t u; } cv;
    cv.h = __hip_bfloat162(__float2bfloat16(a), __float2bfloat16(b));
    return cv.u;
}
__device__ __forceinline__ unsigned short bf16bits(float a) {
    union { __hip_bfloat16 b; unsigned short u; } cv;
    cv.b = __float2bfloat16(a);
    return cv.u;
}

// ---------------- CSR build ----------------
__global__ void count_kernel(const int* __restrict__ dst, int E, int* __restrict__ count) {
    int e = blockIdx.x * blockDim.x + threadIdx.x;
    if (e < E) atomicAdd(&count[dst[e]], 1);
}

__global__ __launch_bounds__(256) void scan_partial_kernel(const int* __restrict__ count, int n,
                                                           int* __restrict__ partial) {
    __shared__ int red[256];
    int t = threadIdx.x;
    int base = blockIdx.x * 1024 + t * 4;
    int s = 0;
#pragma unroll
    for (int i = 0; i < 4; ++i) {
        int idx = base + i;
        if (idx < n) s += count[idx];
    }
    red[t] = s;
    __syncthreads();
    for (int o = 128; o > 0; o >>= 1) {
        if (t < o) red[t] += red[t + o];
        __syncthreads();
    }
    if (t == 0) partial[blockIdx.x] = red[0];
}

__global__ __launch_bounds__(256) void scan_offsets_kernel(int* __restrict__ partial, int nb,
                                                           int* __restrict__ row_ptr, int n) {
    __shared__ int sc[256];
    int t = threadIdx.x;
    sc[t] = (t < nb) ? partial[t] : 0;
    __syncthreads();
    for (int o = 1; o < 256; o <<= 1) {
        int v = sc[t];
        int u = (t >= o) ? sc[t - o] : 0;
        __syncthreads();
        sc[t] = v + u;
        __syncthreads();
    }
    if (t < nb) partial[t] = (t > 0) ? sc[t - 1] : 0;  // exclusive
    if (t == 0) row_ptr[n] = sc[255];
}

__global__ __launch_bounds__(256) void scan_write_kernel(const int* __restrict__ count, int n,
                                                         const int* __restrict__ partial,
                                                         int* __restrict__ row_ptr,
                                                         int* __restrict__ cursor,
                                                         float* __restrict__ dinv) {
    __shared__ int sc[256];
    int t = threadIdx.x;
    int base = blockIdx.x * 1024 + t * 4;
    int c[4];
    int s = 0;
#pragma unroll
    for (int i = 0; i < 4; ++i) {
        int idx = base + i;
        c[i] = (idx < n) ? count[idx] : 0;
        s += c[i];
    }
    sc[t] = s;
    __syncthreads();
    for (int o = 1; o < 256; o <<= 1) {
        int v = sc[t];
        int u = (t >= o) ? sc[t - o] : 0;
        __syncthreads();
        sc[t] = v + u;
        __syncthreads();
    }
    int run = partial[blockIdx.x] + ((t > 0) ? sc[t - 1] : 0);
#pragma unroll
    for (int i = 0; i < 4; ++i) {
        int idx = base + i;
        if (idx < n) {
            row_ptr[idx] = run;
            cursor[idx] = run;
            dinv[idx] = rsqrtf((float)c[i] + 1.0f);
            run += c[i];
        }
    }
}

// Packed adjacency entry: .x = src index, .y = bits(dinv[src]).
__global__ void fill_kernel(const int* __restrict__ src, const int* __restrict__ dst, int E,
                            const float* __restrict__ dinv,
                            int* __restrict__ cursor, int2* __restrict__ colw) {
    int e = blockIdx.x * blockDim.x + threadIdx.x;
    if (e < E) {
        int s = src[e];
        float w = dinv[s];
        int p = atomicAdd(&cursor[dst[e]], 1);
        long long packed = ((long long)(unsigned)__float_as_uint(w) << 32) | (unsigned)s;
        __builtin_nontemporal_store(packed, (long long*)&colw[p]);
    }
}

// ---------------- GEMMs (4x4 register tile, K-chunked LDS) ----------------
#define FMA16(a, b, acc)                                                     \
    acc[0][0] = fmaf(a.x, b.x, acc[0][0]); acc[0][1] = fmaf(a.x, b.y, acc[0][1]); \
    acc[0][2] = fmaf(a.x, b.z, acc[0][2]); acc[0][3] = fmaf(a.x, b.w, acc[0][3]); \
    acc[1][0] = fmaf(a.y, b.x, acc[1][0]); acc[1][1] = fmaf(a.y, b.y, acc[1][1]); \
    acc[1][2] = fmaf(a.y, b.z, acc[1][2]); acc[1][3] = fmaf(a.y, b.w, acc[1][3]); \
    acc[2][0] = fmaf(a.z, b.x, acc[2][0]); acc[2][1] = fmaf(a.z, b.y, acc[2][1]); \
    acc[2][2] = fmaf(a.z, b.z, acc[2][2]); acc[2][3] = fmaf(a.z, b.w, acc[2][3]); \
    acc[3][0] = fmaf(a.w, b.x, acc[3][0]); acc[3][1] = fmaf(a.w, b.y, acc[3][1]); \
    acc[3][2] = fmaf(a.w, b.z, acc[3][2]); acc[3][3] = fmaf(a.w, b.w, acc[3][3]);

__global__ __launch_bounds__(256) void gemm1_kernel(const float* __restrict__ In,
                                                    const float* __restrict__ W,
                                                    __hip_bfloat16* __restrict__ Out, int n) {
    __shared__ float sInT[32][32];   // [k][row]
    __shared__ float sW[32][128];
    int t = threadIdx.x;
    int tr = t >> 5, tc = t & 31;
    int rbase = blockIdx.x * 32;
    float acc[4][4] = {};
    for (int kt = 0; kt < 128; kt += 32) {
        {
            int r = t >> 3, k4 = (t & 7) << 2;
            int gr = rbase + r;
            float4 v = make_float4(0.f, 0.f, 0.f, 0.f);
            if (gr < n) v = *(const float4*)&In[(size_t)gr * 128 + kt + k4];
            sInT[k4 + 0][r] = v.x; sInT[k4 + 1][r] = v.y;
            sInT[k4 + 2][r] = v.z; sInT[k4 + 3][r] = v.w;
        }
        {
            const float4* Wv = (const float4*)&W[(size_t)kt * 128];
            float4* sWv = (float4*)&sW[0][0];
            for (int i = t; i < 1024; i += 256) sWv[i] = Wv[i];
        }
        __syncthreads();
#pragma unroll
        for (int k = 0; k < 32; ++k) {
            float4 a = *(const float4*)&sInT[k][tr << 2];
            float4 b = *(const float4*)&sW[k][tc << 2];
            FMA16(a, b, acc)
        }
        __syncthreads();
    }
#pragma unroll
    for (int i = 0; i < 4; ++i) {
        int gr = rbase + (tr << 2) + i;
        if (gr < n) {
            uint2 pk;
            pk.x = pk2(acc[i][0], acc[i][1]);
            pk.y = pk2(acc[i][2], acc[i][3]);
            *(uint2*)((uint32_t*)Out + (size_t)gr * 64 + (tc << 1)) = pk;
        }
    }
}

__global__ __launch_bounds__(256) void gemmA_kernel(const __hip_bfloat16* __restrict__ In,
                                                    const float* __restrict__ W,
                                                    __hip_bfloat16* __restrict__ Out, int n) {
    __shared__ float sInT[32][64];
    __shared__ float sW[32][64];
    int t = threadIdx.x;
    int tr = t >> 4, tc = t & 15;
    int rbase = blockIdx.x * 64;
    float acc[4][4] = {};
    const uint32_t* Inu = (const uint32_t*)In;
    for (int kt = 0; kt < 128; kt += 32) {
        for (int i = t; i < 1024; i += 256) {
            int r = i >> 4, ku = i & 15;
            int gr = rbase + r;
            uint32_t u = (gr < n) ? Inu[(size_t)gr * 64 + (kt >> 1) + ku] : 0u;
            sInT[2 * ku][r] = lo16f(u);
            sInT[2 * ku + 1][r] = hi16f(u);
        }
        {
            const float4* Wv = (const float4*)&W[(size_t)kt * 64];
            float4* sWv = (float4*)&sW[0][0];
            for (int i = t; i < 512; i += 256) sWv[i] = Wv[i];
        }
        __syncthreads();
#pragma unroll
        for (int k = 0; k < 32; ++k) {
            float4 a = *(const float4*)&sInT[k][tr << 2];
            float4 b = *(const float4*)&sW[k][tc << 2];
            FMA16(a, b, acc)
        }
        __syncthreads();
    }
#pragma unroll
    for (int i = 0; i < 4; ++i) {
        int gr = rbase + (tr << 2) + i;
        if (gr < n) {
            uint2 pk;
            pk.x = pk2(acc[i][0], acc[i][1]);
            pk.y = pk2(acc[i][2], acc[i][3]);
            *(uint2*)((uint32_t*)Out + (size_t)gr * 32 + (tc << 1)) = pk;
        }
    }
}

__global__ __launch_bounds__(256) void gemmB_kernel(const float* __restrict__ In,
                                                    const float* __restrict__ W,
                                                    __hip_bfloat16* __restrict__ Out, int n) {
    __shared__ float sInT[32][64];
    __shared__ float sW[32][64];
    int t = threadIdx.x;
    int tr = t >> 4, tc = t & 15;
    int rbase = blockIdx.x * 64;
    float acc[4][4] = {};
    for (int kt = 0; kt < 64; kt += 32) {
        for (int i = t; i < 512; i += 256) {
            int r = i >> 3, k4 = (i & 7) << 2;
            int gr = rbase + r;
            float4 v = make_float4(0.f, 0.f, 0.f, 0.f);
            if (gr < n) v = *(const float4*)&In[(size_t)gr * 64 + kt + k4];
            sInT[k4 + 0][r] = v.x; sInT[k4 + 1][r] = v.y;
            sInT[k4 + 2][r] = v.z; sInT[k4 + 3][r] = v.w;
        }
        {
            const float4* Wv = (const float4*)&W[(size_t)kt * 64];
            float4* sWv = (float4*)&sW[0][0];
            for (int i = t; i < 512; i += 256) sWv[i] = Wv[i];
        }
        __syncthreads();
#pragma unroll
        for (int k = 0; k < 32; ++k) {
            float4 a = *(const float4*)&sInT[k][tr << 2];
            float4 b = *(const float4*)&sW[k][tc << 2];
            FMA16(a, b, acc)
        }
        __syncthreads();
    }
#pragma unroll
    for (int i = 0; i < 4; ++i) {
        int gr = rbase + (tr << 2) + i;
        if (gr < n) {
            uint2 pk;
            pk.x = pk2(acc[i][0], acc[i][1]);
            pk.y = pk2(acc[i][2], acc[i][3]);
            *(uint2*)((uint32_t*)Out + (size_t)gr * 32 + (tc << 1)) = pk;
        }
    }
}

// ---------------- Gathers (one wave per dst row, unroll-4, packed adjacency) ----
__global__ __launch_bounds__(256) void gather128_kernel(
    const __hip_bfloat16* __restrict__ xw, const int* __restrict__ row_ptr,
    const int2* __restrict__ colw, const float* __restrict__ dinv,
    const float* __restrict__ b1, __hip_bfloat16* __restrict__ h1, int n) {
    int w = threadIdx.x >> 6, l = threadIdx.x & 63;
    int d = blockIdx.x * 4 + w;
    if (d >= n) return;
    float dd = dinv[d];
    int p0 = row_ptr[d], p1 = row_ptr[d + 1];
    const uint32_t* X = (const uint32_t*)xw;
    uint32_t v = X[(size_t)d * 64 + l];
    float a0 = dd * lo16f(v), a1 = dd * hi16f(v);
    int e = p0;
    for (; e + 4 <= p1; e += 4) {
        int2 c0 = colw[e], c1 = colw[e + 1], c2 = colw[e + 2], c3 = colw[e + 3];
        uint32_t v0 = X[(size_t)c0.x * 64 + l];
        uint32_t v1 = X[(size_t)c1.x * 64 + l];
        uint32_t v2 = X[(size_t)c2.x * 64 + l];
        uint32_t v3 = X[(size_t)c3.x * 64 + l];
        float w0 = __int_as_float(c0.y), w1 = __int_as_float(c1.y);
        float w2 = __int_as_float(c2.y), w3 = __int_as_float(c3.y);
        a0 = fmaf(w0, lo16f(v0), a0); a1 = fmaf(w0, hi16f(v0), a1);
        a0 = fmaf(w1, lo16f(v1), a0); a1 = fmaf(w1, hi16f(v1), a1);
        a0 = fmaf(w2, lo16f(v2), a0); a1 = fmaf(w2, hi16f(v2), a1);
        a0 = fmaf(w3, lo16f(v3), a0); a1 = fmaf(w3, hi16f(v3), a1);
    }
    for (; e < p1; ++e) {
        int2 c = colw[e];
        uint32_t vv = X[(size_t)c.x * 64 + l];
        float ww = __int_as_float(c.y);
        a0 = fmaf(ww, lo16f(vv), a0); a1 = fmaf(ww, hi16f(vv), a1);
    }
    a0 = fmaxf(fmaf(dd, a0, b1[2 * l]), 0.0f);
    a1 = fmaxf(fmaf(dd, a1, b1[2 * l + 1]), 0.0f);
    ((uint32_t*)h1)[(size_t)d * 64 + l] = pk2(a0, a1);
}

// OUT=0: fp32 out; OUT=1: bf16 out.
template<bool RELU, int OUT>
__global__ __launch_bounds__(256) void gather64b_kernel(
    const __hip_bfloat16* __restrict__ xw, const int* __restrict__ row_ptr,
    const int2* __restrict__ colw, const float* __restrict__ dinv,
    const float* __restrict__ b, void* __restrict__ out, int n) {
    int w = threadIdx.x >> 6, l = threadIdx.x & 63;
    int d = blockIdx.x * 4 + w;
    if (d >= n) return;
    float dd = dinv[d];
    int p0 = row_ptr[d], p1 = row_ptr[d + 1];
    const unsigned short* X = (const unsigned short*)xw;
    float a = dd * u16f(X[(size_t)d * 64 + l]);
    int e = p0;
    for (; e + 4 <= p1; e += 4) {
        int2 c0 = colw[e], c1 = colw[e + 1], c2 = colw[e + 2], c3 = colw[e + 3];
        unsigned short v0 = X[(size_t)c0.x * 64 + l];
        unsigned short v1 = X[(size_t)c1.x * 64 + l];
        unsigned short v2 = X[(size_t)c2.x * 64 + l];
        unsigned short v3 = X[(size_t)c3.x * 64 + l];
        a = fmaf(__int_as_float(c0.y), u16f(v0), a);
        a = fmaf(__int_as_float(c1.y), u16f(v1), a);
        a = fmaf(__int_as_float(c2.y), u16f(v2), a);
        a = fmaf(__int_as_float(c3.y), u16f(v3), a);
    }
    for (; e < p1; ++e) {
        int2 c = colw[e];
        a = fmaf(__int_as_float(c.y), u16f(X[(size_t)c.x * 64 + l]), a);
    }
    float r = fmaf(dd, a, b[l]);
    if (RELU) r = fmaxf(r, 0.0f);
    if (OUT == 0) ((float*)out)[(size_t)d * 64 + l] = r;
    else ((unsigned short*)out)[(size_t)d * 64 + l] = bf16bits(r);
}

// ---------------- Score: 2 edges per wave, 32-lane groups, bf16 h3 (128B rows) ----
__global__ void score_kernel(const __hip_bfloat16* __restrict__ h, const int* __restrict__ pos,
                             const int* __restrict__ neg, int Ep, int En,
                             float* __restrict__ out) {
    int wid = (int)(((size_t)blockIdx.x * blockDim.x + threadIdx.x) >> 6);
    int lane = threadIdx.x & 63;
    int g = lane >> 5, sl = lane & 31;
    int ed = wid * 2 + g;
    int tot = Ep + En;
    if (ed >= tot) return;
    int j, i;
    if (ed < Ep) { j = pos[ed]; i = pos[Ep + ed]; }
    else { int e = ed - Ep; j = neg[e]; i = neg[En + e]; }
    const uint32_t* X = (const uint32_t*)h;
    uint32_t vi = X[(size_t)i * 32 + sl];
    uint32_t vj = X[(size_t)j * 32 + sl];
    float v = fmaf(hi16f(vi), hi16f(vj), lo16f(vi) * lo16f(vj));
#pragma unroll
    for (int o = 16; o > 0; o >>= 1) v += __shfl_xor(v, o);
    if (sl == 0) out[ed] = v;
}

extern "C" void kernel_launch(void* const* d_in, const int* in_sizes, int n_in,
                              void* d_out, int out_size, void* d_ws, size_t ws_size,
                              hipStream_t stream) {
    const float* x   = (const float*)d_in[0];
    const int* train = (const int*)d_in[1];
    const int* pos   = (const int*)d_in[2];
    const int* neg   = (const int*)d_in[3];
    const float* W1  = (const float*)d_in[4];
    const float* b1  = (const float*)d_in[5];
    const float* W2  = (const float*)d_in[6];
    const float* b2  = (const float*)d_in[7];
    const float* W3  = (const float*)d_in[8];
    const float* b3  = (const float*)d_in[9];

    const int n  = in_sizes[0] / 128;
    const int E  = in_sizes[1] / 2;
    const int Ep = in_sizes[2] / 2;
    const int En = in_sizes[3] / 2;

    // Workspace (~78.6 MB)
    char* wp = (char*)d_ws;
    auto alloc = [&](size_t bytes) { char* r = wp; wp += (bytes + 255) & ~(size_t)255; return r; };
    int*   count   = (int*)alloc((size_t)n * 4);
    int*   row_ptr = (int*)alloc(((size_t)n + 1) * 4);
    int*   cursor  = (int*)alloc((size_t)n * 4);
    int*   partial = (int*)alloc(256 * 4);
    int2*  colw    = (int2*)alloc((size_t)E * 8);
    float* dinv    = (float*)alloc((size_t)n * 4);
    __hip_bfloat16* xw1 = (__hip_bfloat16*)alloc((size_t)n * 128 * 2);  // reused as h3(bf16 n*64)
    __hip_bfloat16* h1  = (__hip_bfloat16*)alloc((size_t)n * 128 * 2);
    __hip_bfloat16* P   = (__hip_bfloat16*)alloc((size_t)n * 64 * 2);   // xw2, later xw3
    __hip_bfloat16* h3  = xw1;
    __hip_bfloat16* xw3 = P;

    float* out_scores = (float*)d_out;
    float* out_embed  = out_scores + (Ep + En);  // h2 lives here directly

    const int eb256 = (E + 255) / 256;
    const int nbs = (n + 1023) / 1024;

    // CSR build + norm coefficients
    hipMemsetAsync(count, 0, (size_t)n * sizeof(int), stream);
    count_kernel<<<eb256, 256, 0, stream>>>(train + E, E, count);
    scan_partial_kernel<<<nbs, 256, 0, stream>>>(count, n, partial);
    scan_offsets_kernel<<<1, 256, 0, stream>>>(partial, nbs, row_ptr, n);
    scan_write_kernel<<<nbs, 256, 0, stream>>>(count, n, partial, row_ptr, cursor, dinv);
    fill_kernel<<<eb256, 256, 0, stream>>>(train, train + E, E, dinv, cursor, colw);

    // Layer 1
    gemm1_kernel<<<(n + 31) / 32, 256, 0, stream>>>(x, W1, xw1, n);
    gather128_kernel<<<(n + 3) / 4, 256, 0, stream>>>(xw1, row_ptr, colw, dinv, b1, h1, n);
    gemmA_kernel<<<(n + 63) / 64, 256, 0, stream>>>(h1, W2, P, n);

    // Layer 2 (h2 written straight into out_embed, fp32)
    gather64b_kernel<true, 0><<<(n + 3) / 4, 256, 0, stream>>>(
        P, row_ptr, colw, dinv, b2, out_embed, n);

    // Layer 3 (h3 emitted bf16 for the score stage)
    gemmB_kernel<<<(n + 63) / 64, 256, 0, stream>>>(out_embed, W3, xw3, n);
    gather64b_kernel<false, 1><<<(n + 3) / 4, 256, 0, stream>>>(
        xw3, row_ptr, colw, dinv, b3, h3, n);

    // Scores: 2 edges per wave
    {
        int waves = (Ep + En + 1) / 2;
        score_kernel<<<(int)(((size_t)waves * 64 + 255) / 256), 256, 0, stream>>>(
            h3, pos, neg, Ep, En, out_scores);
    }
}

// Round 10
// 518.290 us; speedup vs baseline: 1.1272x; 1.1272x over previous
//
#include <hip/hip_runtime.h>
#include <hip/hip_bf16.h>

// GCN link prediction. Inputs fp32+int32; OUTPUT fp32 (scores[1M] ++ embed[n*64]).
// CSR gather + bf16 feature tables (fp32 math), register-tiled 4x4 GEMMs,
// device-wide scan, radix-partitioned CSR build (atomic-cursor fill was
// random partial-line scatter bound: 64B HBM write per 8B store).

#define ECH 4096      // edges per partition chunk
#define SHIFT 8       // dsts per bucket = 256
#define MAXNB 512     // max buckets (n <= 131072)

__device__ __forceinline__ float lo16f(uint32_t u) { uint32_t x = u << 16; float f; __builtin_memcpy(&f, &x, 4); return f; }
__device__ __forceinline__ float hi16f(uint32_t u) { uint32_t x = u & 0xffff0000u; float f; __builtin_memcpy(&f, &x, 4); return f; }
__device__ __forceinline__ float u16f(unsigned short u) { uint32_t x = (uint32_t)u << 16; float f; __builtin_memcpy(&f, &x, 4); return f; }
__device__ __forceinline__ uint32_t pk2(float a, float b) {
    union { __hip_bfloat162 h; uint32_t u; } cv;
    cv.h = __hip_bfloat162(__float2bfloat16(a), __float2bfloat16(b));
    return cv.u;
}
__device__ __forceinline__ unsigned short bf16bits(float a) {
    union { __hip_bfloat16 b; unsigned short u; } cv;
    cv.b = __float2bfloat16(a);
    return cv.u;
}

// ---------------- degree count + row_ptr scan ----------------
__global__ void count_kernel(const int* __restrict__ dst, int E, int* __restrict__ count) {
    int e = blockIdx.x * blockDim.x + threadIdx.x;
    if (e < E) atomicAdd(&count[dst[e]], 1);
}

__global__ __launch_bounds__(256) void scan_partial_kernel(const int* __restrict__ count, int n,
                                                           int* __restrict__ partial) {
    __shared__ int red[256];
    int t = threadIdx.x;
    int base = blockIdx.x * 1024 + t * 4;
    int s = 0;
#pragma unroll
    for (int i = 0; i < 4; ++i) {
        int idx = base + i;
        if (idx < n) s += count[idx];
    }
    red[t] = s;
    __syncthreads();
    for (int o = 128; o > 0; o >>= 1) {
        if (t < o) red[t] += red[t + o];
        __syncthreads();
    }
    if (t == 0) partial[blockIdx.x] = red[0];
}

__global__ __launch_bounds__(256) void scan_offsets_kernel(int* __restrict__ partial, int nb,
                                                           int* __restrict__ row_ptr, int n) {
    __shared__ int sc[256];
    int t = threadIdx.x;
    sc[t] = (t < nb) ? partial[t] : 0;
    __syncthreads();
    for (int o = 1; o < 256; o <<= 1) {
        int v = sc[t];
        int u = (t >= o) ? sc[t - o] : 0;
        __syncthreads();
        sc[t] = v + u;
        __syncthreads();
    }
    if (t < nb) partial[t] = (t > 0) ? sc[t - 1] : 0;  // exclusive
    if (t == 0) row_ptr[n] = sc[255];
}

__global__ __launch_bounds__(256) void scan_write_kernel(const int* __restrict__ count, int n,
                                                         const int* __restrict__ partial,
                                                         int* __restrict__ row_ptr,
                                                         float* __restrict__ dinv) {
    __shared__ int sc[256];
    int t = threadIdx.x;
    int base = blockIdx.x * 1024 + t * 4;
    int c[4];
    int s = 0;
#pragma unroll
    for (int i = 0; i < 4; ++i) {
        int idx = base + i;
        c[i] = (idx < n) ? count[idx] : 0;
        s += c[i];
    }
    sc[t] = s;
    __syncthreads();
    for (int o = 1; o < 256; o <<= 1) {
        int v = sc[t];
        int u = (t >= o) ? sc[t - o] : 0;
        __syncthreads();
        sc[t] = v + u;
        __syncthreads();
    }
    int run = partial[blockIdx.x] + ((t > 0) ? sc[t - 1] : 0);
#pragma unroll
    for (int i = 0; i < 4; ++i) {
        int idx = base + i;
        if (idx < n) {
            row_ptr[idx] = run;
            dinv[idx] = rsqrtf((float)c[i] + 1.0f);
            run += c[i];
        }
    }
}

// ---------------- radix partition: edges -> buckets -> CSR ----------------
// Phase A: per-chunk histogram over buckets.
__global__ __launch_bounds__(256) void part_hist_kernel(const int* __restrict__ dst, int E,
                                                        int B, int NB, int* __restrict__ histG) {
    __shared__ int h[MAXNB];
    int t = threadIdx.x, blk = blockIdx.x;
    for (int i = t; i < NB; i += 256) h[i] = 0;
    __syncthreads();
    int lo = blk * ECH, hi = min(lo + ECH, E);
    for (int i = lo + t; i < hi; i += 256) atomicAdd(&h[dst[i] >> SHIFT], 1);
    __syncthreads();
    for (int k = t; k < NB; k += 256) histG[(size_t)k * B + blk] = h[k];
}

// Phase B1: per bucket (block=bucket), exclusive scan over blocks in place; total out.
__global__ __launch_bounds__(256) void part_scan_kernel(int* __restrict__ histG, int B,
                                                        int* __restrict__ bucketTotal) {
    __shared__ int sc[1024];   // supports B <= 1024
    int k = blockIdx.x, t = threadIdx.x;
    for (int i = t; i < 1024; i += 256) sc[i] = (i < B) ? histG[(size_t)k * B + i] : 0;
    __syncthreads();
    for (int o = 1; o < 1024; o <<= 1) {
        int v[4];
#pragma unroll
        for (int j = 0; j < 4; ++j) { int i = t + j * 256; v[j] = (i >= o) ? sc[i - o] : 0; }
        __syncthreads();
#pragma unroll
        for (int j = 0; j < 4; ++j) sc[t + j * 256] += v[j];
        __syncthreads();
    }
    for (int i = t; i < B; i += 256) histG[(size_t)k * B + i] = (i > 0) ? sc[i - 1] : 0;
    if (t == 0) bucketTotal[k] = sc[B - 1];
}

// Phase B2: exclusive scan of bucket totals -> bucket bases.
__global__ __launch_bounds__(256) void bucket_base_kernel(const int* __restrict__ bucketTotal,
                                                          int NB, int* __restrict__ bucketBase) {
    __shared__ int sc[MAXNB];
    int t = threadIdx.x;
    for (int i = t; i < MAXNB; i += 256) sc[i] = (i < NB) ? bucketTotal[i] : 0;
    __syncthreads();
    for (int o = 1; o < MAXNB; o <<= 1) {
        int v[MAXNB / 256];
#pragma unroll
        for (int j = 0; j < MAXNB / 256; ++j) { int i = t + j * 256; v[j] = (i >= o) ? sc[i - o] : 0; }
        __syncthreads();
#pragma unroll
        for (int j = 0; j < MAXNB / 256; ++j) sc[t + j * 256] += v[j];
        __syncthreads();
    }
    for (int i = t; i < NB; i += 256) bucketBase[i] = (i > 0) ? sc[i - 1] : 0;
}

// Phase C: scatter edges into bucket-grouped bedges; (block,bucket) ranges are exclusive.
__global__ __launch_bounds__(256) void part_scatter_kernel(
    const int* __restrict__ src, const int* __restrict__ dst, int E, int B, int NB,
    const int* __restrict__ histG, const int* __restrict__ bucketBase,
    int2* __restrict__ bedges) {
    __shared__ int cur[MAXNB];
    int t = threadIdx.x, blk = blockIdx.x;
    for (int k = t; k < NB; k += 256) cur[k] = bucketBase[k] + histG[(size_t)k * B + blk];
    __syncthreads();
    int lo = blk * ECH, hi = min(lo + ECH, E);
    for (int i = lo + t; i < hi; i += 256) {
        int s = src[i], d = dst[i];
        int p = atomicAdd(&cur[d >> SHIFT], 1);
        bedges[p] = make_int2(s, d);
    }
}

// Phase D: one block per bucket; LDS per-dst cursors; CSR region block-exclusive.
__global__ __launch_bounds__(256) void csr_fill_kernel(
    const int2* __restrict__ bedges, const int* __restrict__ bucketBase,
    const int* __restrict__ bucketTotal, const int* __restrict__ row_ptr,
    const float* __restrict__ dinv, int n, int2* __restrict__ colw) {
    __shared__ int cur[1 << SHIFT];
    int k = blockIdx.x, t = threadIdx.x;
    int d0 = k << SHIFT;
    for (int i = t; i < (1 << SHIFT); i += 256) {
        int d = d0 + i;
        cur[i] = (d < n) ? row_ptr[d] : 0;
    }
    __syncthreads();
    int base = bucketBase[k], cnt = bucketTotal[k];
    for (int i = t; i < cnt; i += 256) {
        int2 e = bedges[base + i];
        float w = dinv[e.x];
        int p = atomicAdd(&cur[e.y - d0], 1);
        colw[p] = make_int2(e.x, __float_as_int(w));
    }
}

// ---------------- GEMMs (4x4 register tile, K-chunked LDS) ----------------
#define FMA16(a, b, acc)                                                     \
    acc[0][0] = fmaf(a.x, b.x, acc[0][0]); acc[0][1] = fmaf(a.x, b.y, acc[0][1]); \
    acc[0][2] = fmaf(a.x, b.z, acc[0][2]); acc[0][3] = fmaf(a.x, b.w, acc[0][3]); \
    acc[1][0] = fmaf(a.y, b.x, acc[1][0]); acc[1][1] = fmaf(a.y, b.y, acc[1][1]); \
    acc[1][2] = fmaf(a.y, b.z, acc[1][2]); acc[1][3] = fmaf(a.y, b.w, acc[1][3]); \
    acc[2][0] = fmaf(a.z, b.x, acc[2][0]); acc[2][1] = fmaf(a.z, b.y, acc[2][1]); \
    acc[2][2] = fmaf(a.z, b.z, acc[2][2]); acc[2][3] = fmaf(a.z, b.w, acc[2][3]); \
    acc[3][0] = fmaf(a.w, b.x, acc[3][0]); acc[3][1] = fmaf(a.w, b.y, acc[3][1]); \
    acc[3][2] = fmaf(a.w, b.z, acc[3][2]); acc[3][3] = fmaf(a.w, b.w, acc[3][3]);

__global__ __launch_bounds__(256) void gemm1_kernel(const float* __restrict__ In,
                                                    const float* __restrict__ W,
                                                    __hip_bfloat16* __restrict__ Out, int n) {
    __shared__ float sInT[32][32];   // [k][row]
    __shared__ float sW[32][128];
    int t = threadIdx.x;
    int tr = t >> 5, tc = t & 31;
    int rbase = blockIdx.x * 32;
    float acc[4][4] = {};
    for (int kt = 0; kt < 128; kt += 32) {
        {
            int r = t >> 3, k4 = (t & 7) << 2;
            int gr = rbase + r;
            float4 v = make_float4(0.f, 0.f, 0.f, 0.f);
            if (gr < n) v = *(const float4*)&In[(size_t)gr * 128 + kt + k4];
            sInT[k4 + 0][r] = v.x; sInT[k4 + 1][r] = v.y;
            sInT[k4 + 2][r] = v.z; sInT[k4 + 3][r] = v.w;
        }
        {
            const float4* Wv = (const float4*)&W[(size_t)kt * 128];
            float4* sWv = (float4*)&sW[0][0];
            for (int i = t; i < 1024; i += 256) sWv[i] = Wv[i];
        }
        __syncthreads();
#pragma unroll
        for (int k = 0; k < 32; ++k) {
            float4 a = *(const float4*)&sInT[k][tr << 2];
            float4 b = *(const float4*)&sW[k][tc << 2];
            FMA16(a, b, acc)
        }
        __syncthreads();
    }
#pragma unroll
    for (int i = 0; i < 4; ++i) {
        int gr = rbase + (tr << 2) + i;
        if (gr < n) {
            uint2 pk;
            pk.x = pk2(acc[i][0], acc[i][1]);
            pk.y = pk2(acc[i][2], acc[i][3]);
            *(uint2*)((uint32_t*)Out + (size_t)gr * 64 + (tc << 1)) = pk;
        }
    }
}

__global__ __launch_bounds__(256) void gemmA_kernel(const __hip_bfloat16* __restrict__ In,
                                                    const float* __restrict__ W,
                                                    __hip_bfloat16* __restrict__ Out, int n) {
    __shared__ float sInT[32][64];
    __shared__ float sW[32][64];
    int t = threadIdx.x;
    int tr = t >> 4, tc = t & 15;
    int rbase = blockIdx.x * 64;
    float acc[4][4] = {};
    const uint32_t* Inu = (const uint32_t*)In;
    for (int kt = 0; kt < 128; kt += 32) {
        for (int i = t; i < 1024; i += 256) {
            int r = i >> 4, ku = i & 15;
            int gr = rbase + r;
            uint32_t u = (gr < n) ? Inu[(size_t)gr * 64 + (kt >> 1) + ku] : 0u;
            sInT[2 * ku][r] = lo16f(u);
            sInT[2 * ku + 1][r] = hi16f(u);
        }
        {
            const float4* Wv = (const float4*)&W[(size_t)kt * 64];
            float4* sWv = (float4*)&sW[0][0];
            for (int i = t; i < 512; i += 256) sWv[i] = Wv[i];
        }
        __syncthreads();
#pragma unroll
        for (int k = 0; k < 32; ++k) {
            float4 a = *(const float4*)&sInT[k][tr << 2];
            float4 b = *(const float4*)&sW[k][tc << 2];
            FMA16(a, b, acc)
        }
        __syncthreads();
    }
#pragma unroll
    for (int i = 0; i < 4; ++i) {
        int gr = rbase + (tr << 2) + i;
        if (gr < n) {
            uint2 pk;
            pk.x = pk2(acc[i][0], acc[i][1]);
            pk.y = pk2(acc[i][2], acc[i][3]);
            *(uint2*)((uint32_t*)Out + (size_t)gr * 32 + (tc << 1)) = pk;
        }
    }
}

__global__ __launch_bounds__(256) void gemmB_kernel(const float* __restrict__ In,
                                                    const float* __restrict__ W,
                                                    __hip_bfloat16* __restrict__ Out, int n) {
    __shared__ float sInT[32][64];
    __shared__ float sW[32][64];
    int t = threadIdx.x;
    int tr = t >> 4, tc = t & 15;
    int rbase = blockIdx.x * 64;
    float acc[4][4] = {};
    for (int kt = 0; kt < 64; kt += 32) {
        for (int i = t; i < 512; i += 256) {
            int r = i >> 3, k4 = (i & 7) << 2;
            int gr = rbase + r;
            float4 v = make_float4(0.f, 0.f, 0.f, 0.f);
            if (gr < n) v = *(const float4*)&In[(size_t)gr * 64 + kt + k4];
            sInT[k4 + 0][r] = v.x; sInT[k4 + 1][r] = v.y;
            sInT[k4 + 2][r] = v.z; sInT[k4 + 3][r] = v.w;
        }
        {
            const float4* Wv = (const float4*)&W[(size_t)kt * 64];
            float4* sWv = (float4*)&sW[0][0];
            for (int i = t; i < 512; i += 256) sWv[i] = Wv[i];
        }
        __syncthreads();
#pragma unroll
        for (int k = 0; k < 32; ++k) {
            float4 a = *(const float4*)&sInT[k][tr << 2];
            float4 b = *(const float4*)&sW[k][tc << 2];
            FMA16(a, b, acc)
        }
        __syncthreads();
    }
#pragma unroll
    for (int i = 0; i < 4; ++i) {
        int gr = rbase + (tr << 2) + i;
        if (gr < n) {
            uint2 pk;
            pk.x = pk2(acc[i][0], acc[i][1]);
            pk.y = pk2(acc[i][2], acc[i][3]);
            *(uint2*)((uint32_t*)Out + (size_t)gr * 32 + (tc << 1)) = pk;
        }
    }
}

// ---------------- Gathers (one wave per dst row, unroll-4, packed adjacency) ----
__global__ __launch_bounds__(256) void gather128_kernel(
    const __hip_bfloat16* __restrict__ xw, const int* __restrict__ row_ptr,
    const int2* __restrict__ colw, const float* __restrict__ dinv,
    const float* __restrict__ b1, __hip_bfloat16* __restrict__ h1, int n) {
    int w = threadIdx.x >> 6, l = threadIdx.x & 63;
    int d = blockIdx.x * 4 + w;
    if (d >= n) return;
    float dd = dinv[d];
    int p0 = row_ptr[d], p1 = row_ptr[d + 1];
    const uint32_t* X = (const uint32_t*)xw;
    uint32_t v = X[(size_t)d * 64 + l];
    float a0 = dd * lo16f(v), a1 = dd * hi16f(v);
    int e = p0;
    for (; e + 4 <= p1; e += 4) {
        int2 c0 = colw[e], c1 = colw[e + 1], c2 = colw[e + 2], c3 = colw[e + 3];
        uint32_t v0 = X[(size_t)c0.x * 64 + l];
        uint32_t v1 = X[(size_t)c1.x * 64 + l];
        uint32_t v2 = X[(size_t)c2.x * 64 + l];
        uint32_t v3 = X[(size_t)c3.x * 64 + l];
        float w0 = __int_as_float(c0.y), w1 = __int_as_float(c1.y);
        float w2 = __int_as_float(c2.y), w3 = __int_as_float(c3.y);
        a0 = fmaf(w0, lo16f(v0), a0); a1 = fmaf(w0, hi16f(v0), a1);
        a0 = fmaf(w1, lo16f(v1), a0); a1 = fmaf(w1, hi16f(v1), a1);
        a0 = fmaf(w2, lo16f(v2), a0); a1 = fmaf(w2, hi16f(v2), a1);
        a0 = fmaf(w3, lo16f(v3), a0); a1 = fmaf(w3, hi16f(v3), a1);
    }
    for (; e < p1; ++e) {
        int2 c = colw[e];
        uint32_t vv = X[(size_t)c.x * 64 + l];
        float ww = __int_as_float(c.y);
        a0 = fmaf(ww, lo16f(vv), a0); a1 = fmaf(ww, hi16f(vv), a1);
    }
    a0 = fmaxf(fmaf(dd, a0, b1[2 * l]), 0.0f);
    a1 = fmaxf(fmaf(dd, a1, b1[2 * l + 1]), 0.0f);
    ((uint32_t*)h1)[(size_t)d * 64 + l] = pk2(a0, a1);
}

// OUT=0: fp32 out; OUT=1: bf16 out.
template<bool RELU, int OUT>
__global__ __launch_bounds__(256) void gather64b_kernel(
    const __hip_bfloat16* __restrict__ xw, const int* __restrict__ row_ptr,
    const int2* __restrict__ colw, const float* __restrict__ dinv,
    const float* __restrict__ b, void* __restrict__ out, int n) {
    int w = threadIdx.x >> 6, l = threadIdx.x & 63;
    int d = blockIdx.x * 4 + w;
    if (d >= n) return;
    float dd = dinv[d];
    int p0 = row_ptr[d], p1 = row_ptr[d + 1];
    const unsigned short* X = (const unsigned short*)xw;
    float a = dd * u16f(X[(size_t)d * 64 + l]);
    int e = p0;
    for (; e + 4 <= p1; e += 4) {
        int2 c0 = colw[e], c1 = colw[e + 1], c2 = colw[e + 2], c3 = colw[e + 3];
        unsigned short v0 = X[(size_t)c0.x * 64 + l];
        unsigned short v1 = X[(size_t)c1.x * 64 + l];
        unsigned short v2 = X[(size_t)c2.x * 64 + l];
        unsigned short v3 = X[(size_t)c3.x * 64 + l];
        a = fmaf(__int_as_float(c0.y), u16f(v0), a);
        a = fmaf(__int_as_float(c1.y), u16f(v1), a);
        a = fmaf(__int_as_float(c2.y), u16f(v2), a);
        a = fmaf(__int_as_float(c3.y), u16f(v3), a);
    }
    for (; e < p1; ++e) {
        int2 c = colw[e];
        a = fmaf(__int_as_float(c.y), u16f(X[(size_t)c.x * 64 + l]), a);
    }
    float r = fmaf(dd, a, b[l]);
    if (RELU) r = fmaxf(r, 0.0f);
    if (OUT == 0) ((float*)out)[(size_t)d * 64 + l] = r;
    else ((unsigned short*)out)[(size_t)d * 64 + l] = bf16bits(r);
}

// ---------------- Score: 2 edges per wave, 32-lane groups, bf16 h3 (128B rows) ----
__global__ void score_kernel(const __hip_bfloat16* __restrict__ h, const int* __restrict__ pos,
                             const int* __restrict__ neg, int Ep, int En,
                             float* __restrict__ out) {
    int wid = (int)(((size_t)blockIdx.x * blockDim.x + threadIdx.x) >> 6);
    int lane = threadIdx.x & 63;
    int g = lane >> 5, sl = lane & 31;
    int ed = wid * 2 + g;
    int tot = Ep + En;
    if (ed >= tot) return;
    int j, i;
    if (ed < Ep) { j = pos[ed]; i = pos[Ep + ed]; }
    else { int e = ed - Ep; j = neg[e]; i = neg[En + e]; }
    const uint32_t* X = (const uint32_t*)h;
    uint32_t vi = X[(size_t)i * 32 + sl];
    uint32_t vj = X[(size_t)j * 32 + sl];
    float v = fmaf(hi16f(vi), hi16f(vj), lo16f(vi) * lo16f(vj));
#pragma unroll
    for (int o = 16; o > 0; o >>= 1) v += __shfl_xor(v, o);
    if (sl == 0) out[ed] = v;
}

extern "C" void kernel_launch(void* const* d_in, const int* in_sizes, int n_in,
                              void* d_out, int out_size, void* d_ws, size_t ws_size,
                              hipStream_t stream) {
    const float* x   = (const float*)d_in[0];
    const int* train = (const int*)d_in[1];
    const int* pos   = (const int*)d_in[2];
    const int* neg   = (const int*)d_in[3];
    const float* W1  = (const float*)d_in[4];
    const float* b1  = (const float*)d_in[5];
    const float* W2  = (const float*)d_in[6];
    const float* b2  = (const float*)d_in[7];
    const float* W3  = (const float*)d_in[8];
    const float* b3  = (const float*)d_in[9];

    const int n  = in_sizes[0] / 128;
    const int E  = in_sizes[1] / 2;
    const int Ep = in_sizes[2] / 2;
    const int En = in_sizes[3] / 2;

    const int B  = (E + ECH - 1) / ECH;         // partition chunks (391 for E=1.6M)
    const int NB = ((n - 1) >> SHIFT) + 1;      // buckets (391 for n=100K)

    // Workspace (~78 MB)
    char* wp = (char*)d_ws;
    auto alloc = [&](size_t bytes) { char* r = wp; wp += (bytes + 255) & ~(size_t)255; return r; };
    int*   count    = (int*)alloc((size_t)n * 4);
    int*   row_ptr  = (int*)alloc(((size_t)n + 1) * 4);
    int*   partial  = (int*)alloc(256 * 4);
    int*   bucketTotal = (int*)alloc(MAXNB * 4);
    int*   bucketBase  = (int*)alloc(MAXNB * 4);
    int2*  colw     = (int2*)alloc((size_t)E * 8);
    float* dinv     = (float*)alloc((size_t)n * 4);
    __hip_bfloat16* xw1 = (__hip_bfloat16*)alloc((size_t)n * 128 * 2);  // reused as h3(bf16 n*64)
    __hip_bfloat16* h1  = (__hip_bfloat16*)alloc((size_t)n * 128 * 2);
    __hip_bfloat16* P   = (__hip_bfloat16*)alloc((size_t)n * 64 * 2);   // xw2, later xw3
    __hip_bfloat16* h3  = xw1;
    __hip_bfloat16* xw3 = P;
    int2* bedges = (int2*)h1;       // alias: consumed before h1 is written
    int*  histG  = (int*)P;         // alias: NB*B*4 ~ 612KB, consumed before P is written

    float* out_scores = (float*)d_out;
    float* out_embed  = out_scores + (Ep + En);  // h2 lives here directly

    const int eb256 = (E + 255) / 256;
    const int nbs = (n + 1023) / 1024;

    // degrees -> row_ptr, dinv
    hipMemsetAsync(count, 0, (size_t)n * sizeof(int), stream);
    count_kernel<<<eb256, 256, 0, stream>>>(train + E, E, count);
    scan_partial_kernel<<<nbs, 256, 0, stream>>>(count, n, partial);
    scan_offsets_kernel<<<1, 256, 0, stream>>>(partial, nbs, row_ptr, n);
    scan_write_kernel<<<nbs, 256, 0, stream>>>(count, n, partial, row_ptr, dinv);

    // radix-partitioned CSR build (no global atomics, block-local writes)
    part_hist_kernel<<<B, 256, 0, stream>>>(train + E, E, B, NB, histG);
    part_scan_kernel<<<NB, 256, 0, stream>>>(histG, B, bucketTotal);
    bucket_base_kernel<<<1, 256, 0, stream>>>(bucketTotal, NB, bucketBase);
    part_scatter_kernel<<<B, 256, 0, stream>>>(train, train + E, E, B, NB, histG, bucketBase, bedges);
    csr_fill_kernel<<<NB, 256, 0, stream>>>(bedges, bucketBase, bucketTotal, row_ptr, dinv, n, colw);

    // Layer 1
    gemm1_kernel<<<(n + 31) / 32, 256, 0, stream>>>(x, W1, xw1, n);
    gather128_kernel<<<(n + 3) / 4, 256, 0, stream>>>(xw1, row_ptr, colw, dinv, b1, h1, n);
    gemmA_kernel<<<(n + 63) / 64, 256, 0, stream>>>(h1, W2, P, n);

    // Layer 2 (h2 written straight into out_embed, fp32)
    gather64b_kernel<true, 0><<<(n + 3) / 4, 256, 0, stream>>>(
        P, row_ptr, colw, dinv, b2, out_embed, n);

    // Layer 3 (h3 emitted bf16 for the score stage)
    gemmB_kernel<<<(n + 63) / 64, 256, 0, stream>>>(out_embed, W3, xw3, n);
    gather64b_kernel<false, 1><<<(n + 3) / 4, 256, 0, stream>>>(
        xw3, row_ptr, colw, dinv, b3, h3, n);

    // Scores: 2 edges per wave
    {
        int waves = (Ep + En + 1) / 2;
        score_kernel<<<(int)(((size_t)waves * 64 + 255) / 256), 256, 0, stream>>>(
            h3, pos, neg, Ep, En, out_scores);
    }
}

// Round 11
// 466.560 us; speedup vs baseline: 1.2522x; 1.1109x over previous
//
#include <hip/hip_runtime.h>
#include <hip/hip_bf16.h>

// GCN link prediction. Inputs fp32+int32; OUTPUT fp32 (scores[1M] ++ embed[n*64]).
// CSR gather + bf16 feature tables (fp32 math), register-tiled 4x4 GEMMs,
// device-wide scan, radix-partitioned CSR build, 8-edges-per-wave uint4 score
// (score was issue-bound: 5-step shuffle + u32 loads throttled fetch to 15%).

#define ECH 4096      // edges per partition chunk
#define SHIFT 8       // dsts per bucket = 256
#define MAXNB 512     // max buckets (n <= 131072)

__device__ __forceinline__ float lo16f(uint32_t u) { uint32_t x = u << 16; float f; __builtin_memcpy(&f, &x, 4); return f; }
__device__ __forceinline__ float hi16f(uint32_t u) { uint32_t x = u & 0xffff0000u; float f; __builtin_memcpy(&f, &x, 4); return f; }
__device__ __forceinline__ float u16f(unsigned short u) { uint32_t x = (uint32_t)u << 16; float f; __builtin_memcpy(&f, &x, 4); return f; }
__device__ __forceinline__ uint32_t pk2(float a, float b) {
    union { __hip_bfloat162 h; uint32_t u; } cv;
    cv.h = __hip_bfloat162(__float2bfloat16(a), __float2bfloat16(b));
    return cv.u;
}
__device__ __forceinline__ unsigned short bf16bits(float a) {
    union { __hip_bfloat16 b; unsigned short u; } cv;
    cv.b = __float2bfloat16(a);
    return cv.u;
}

// ---------------- degree count + row_ptr scan ----------------
__global__ void count_kernel(const int* __restrict__ dst, int E, int* __restrict__ count) {
    int e = blockIdx.x * blockDim.x + threadIdx.x;
    if (e < E) atomicAdd(&count[dst[e]], 1);
}

__global__ __launch_bounds__(256) void scan_partial_kernel(const int* __restrict__ count, int n,
                                                           int* __restrict__ partial) {
    __shared__ int red[256];
    int t = threadIdx.x;
    int base = blockIdx.x * 1024 + t * 4;
    int s = 0;
#pragma unroll
    for (int i = 0; i < 4; ++i) {
        int idx = base + i;
        if (idx < n) s += count[idx];
    }
    red[t] = s;
    __syncthreads();
    for (int o = 128; o > 0; o >>= 1) {
        if (t < o) red[t] += red[t + o];
        __syncthreads();
    }
    if (t == 0) partial[blockIdx.x] = red[0];
}

__global__ __launch_bounds__(256) void scan_offsets_kernel(int* __restrict__ partial, int nb,
                                                           int* __restrict__ row_ptr, int n) {
    __shared__ int sc[256];
    int t = threadIdx.x;
    sc[t] = (t < nb) ? partial[t] : 0;
    __syncthreads();
    for (int o = 1; o < 256; o <<= 1) {
        int v = sc[t];
        int u = (t >= o) ? sc[t - o] : 0;
        __syncthreads();
        sc[t] = v + u;
        __syncthreads();
    }
    if (t < nb) partial[t] = (t > 0) ? sc[t - 1] : 0;  // exclusive
    if (t == 0) row_ptr[n] = sc[255];
}

__global__ __launch_bounds__(256) void scan_write_kernel(const int* __restrict__ count, int n,
                                                         const int* __restrict__ partial,
                                                         int* __restrict__ row_ptr,
                                                         float* __restrict__ dinv) {
    __shared__ int sc[256];
    int t = threadIdx.x;
    int base = blockIdx.x * 1024 + t * 4;
    int c[4];
    int s = 0;
#pragma unroll
    for (int i = 0; i < 4; ++i) {
        int idx = base + i;
        c[i] = (idx < n) ? count[idx] : 0;
        s += c[i];
    }
    sc[t] = s;
    __syncthreads();
    for (int o = 1; o < 256; o <<= 1) {
        int v = sc[t];
        int u = (t >= o) ? sc[t - o] : 0;
        __syncthreads();
        sc[t] = v + u;
        __syncthreads();
    }
    int run = partial[blockIdx.x] + ((t > 0) ? sc[t - 1] : 0);
#pragma unroll
    for (int i = 0; i < 4; ++i) {
        int idx = base + i;
        if (idx < n) {
            row_ptr[idx] = run;
            dinv[idx] = rsqrtf((float)c[i] + 1.0f);
            run += c[i];
        }
    }
}

// ---------------- radix partition: edges -> buckets -> CSR ----------------
__global__ __launch_bounds__(256) void part_hist_kernel(const int* __restrict__ dst, int E,
                                                        int B, int NB, int* __restrict__ histG) {
    __shared__ int h[MAXNB];
    int t = threadIdx.x, blk = blockIdx.x;
    for (int i = t; i < NB; i += 256) h[i] = 0;
    __syncthreads();
    int lo = blk * ECH, hi = min(lo + ECH, E);
    for (int i = lo + t; i < hi; i += 256) atomicAdd(&h[dst[i] >> SHIFT], 1);
    __syncthreads();
    for (int k = t; k < NB; k += 256) histG[(size_t)k * B + blk] = h[k];
}

__global__ __launch_bounds__(256) void part_scan_kernel(int* __restrict__ histG, int B,
                                                        int* __restrict__ bucketTotal) {
    __shared__ int sc[1024];   // supports B <= 1024
    int k = blockIdx.x, t = threadIdx.x;
    for (int i = t; i < 1024; i += 256) sc[i] = (i < B) ? histG[(size_t)k * B + i] : 0;
    __syncthreads();
    for (int o = 1; o < 1024; o <<= 1) {
        int v[4];
#pragma unroll
        for (int j = 0; j < 4; ++j) { int i = t + j * 256; v[j] = (i >= o) ? sc[i - o] : 0; }
        __syncthreads();
#pragma unroll
        for (int j = 0; j < 4; ++j) sc[t + j * 256] += v[j];
        __syncthreads();
    }
    for (int i = t; i < B; i += 256) histG[(size_t)k * B + i] = (i > 0) ? sc[i - 1] : 0;
    if (t == 0) bucketTotal[k] = sc[B - 1];
}

__global__ __launch_bounds__(256) void bucket_base_kernel(const int* __restrict__ bucketTotal,
                                                          int NB, int* __restrict__ bucketBase) {
    __shared__ int sc[MAXNB];
    int t = threadIdx.x;
    for (int i = t; i < MAXNB; i += 256) sc[i] = (i < NB) ? bucketTotal[i] : 0;
    __syncthreads();
    for (int o = 1; o < MAXNB; o <<= 1) {
        int v[MAXNB / 256];
#pragma unroll
        for (int j = 0; j < MAXNB / 256; ++j) { int i = t + j * 256; v[j] = (i >= o) ? sc[i - o] : 0; }
        __syncthreads();
#pragma unroll
        for (int j = 0; j < MAXNB / 256; ++j) sc[t + j * 256] += v[j];
        __syncthreads();
    }
    for (int i = t; i < NB; i += 256) bucketBase[i] = (i > 0) ? sc[i - 1] : 0;
}

__global__ __launch_bounds__(256) void part_scatter_kernel(
    const int* __restrict__ src, const int* __restrict__ dst, int E, int B, int NB,
    const int* __restrict__ histG, const int* __restrict__ bucketBase,
    int2* __restrict__ bedges) {
    __shared__ int cur[MAXNB];
    int t = threadIdx.x, blk = blockIdx.x;
    for (int k = t; k < NB; k += 256) cur[k] = bucketBase[k] + histG[(size_t)k * B + blk];
    __syncthreads();
    int lo = blk * ECH, hi = min(lo + ECH, E);
    for (int i = lo + t; i < hi; i += 256) {
        int s = src[i], d = dst[i];
        int p = atomicAdd(&cur[d >> SHIFT], 1);
        bedges[p] = make_int2(s, d);
    }
}

__global__ __launch_bounds__(256) void csr_fill_kernel(
    const int2* __restrict__ bedges, const int* __restrict__ bucketBase,
    const int* __restrict__ bucketTotal, const int* __restrict__ row_ptr,
    const float* __restrict__ dinv, int n, int2* __restrict__ colw) {
    __shared__ int cur[1 << SHIFT];
    int k = blockIdx.x, t = threadIdx.x;
    int d0 = k << SHIFT;
    for (int i = t; i < (1 << SHIFT); i += 256) {
        int d = d0 + i;
        cur[i] = (d < n) ? row_ptr[d] : 0;
    }
    __syncthreads();
    int base = bucketBase[k], cnt = bucketTotal[k];
    for (int i = t; i < cnt; i += 256) {
        int2 e = bedges[base + i];
        float w = dinv[e.x];
        int p = atomicAdd(&cur[e.y - d0], 1);
        colw[p] = make_int2(e.x, __float_as_int(w));
    }
}

// ---------------- GEMMs (4x4 register tile, K-chunked LDS) ----------------
#define FMA16(a, b, acc)                                                     \
    acc[0][0] = fmaf(a.x, b.x, acc[0][0]); acc[0][1] = fmaf(a.x, b.y, acc[0][1]); \
    acc[0][2] = fmaf(a.x, b.z, acc[0][2]); acc[0][3] = fmaf(a.x, b.w, acc[0][3]); \
    acc[1][0] = fmaf(a.y, b.x, acc[1][0]); acc[1][1] = fmaf(a.y, b.y, acc[1][1]); \
    acc[1][2] = fmaf(a.y, b.z, acc[1][2]); acc[1][3] = fmaf(a.y, b.w, acc[1][3]); \
    acc[2][0] = fmaf(a.z, b.x, acc[2][0]); acc[2][1] = fmaf(a.z, b.y, acc[2][1]); \
    acc[2][2] = fmaf(a.z, b.z, acc[2][2]); acc[2][3] = fmaf(a.z, b.w, acc[2][3]); \
    acc[3][0] = fmaf(a.w, b.x, acc[3][0]); acc[3][1] = fmaf(a.w, b.y, acc[3][1]); \
    acc[3][2] = fmaf(a.w, b.z, acc[3][2]); acc[3][3] = fmaf(a.w, b.w, acc[3][3]);

__global__ __launch_bounds__(256) void gemm1_kernel(const float* __restrict__ In,
                                                    const float* __restrict__ W,
                                                    __hip_bfloat16* __restrict__ Out, int n) {
    __shared__ float sInT[32][32];   // [k][row]
    __shared__ float sW[32][128];
    int t = threadIdx.x;
    int tr = t >> 5, tc = t & 31;
    int rbase = blockIdx.x * 32;
    float acc[4][4] = {};
    for (int kt = 0; kt < 128; kt += 32) {
        {
            int r = t >> 3, k4 = (t & 7) << 2;
            int gr = rbase + r;
            float4 v = make_float4(0.f, 0.f, 0.f, 0.f);
            if (gr < n) v = *(const float4*)&In[(size_t)gr * 128 + kt + k4];
            sInT[k4 + 0][r] = v.x; sInT[k4 + 1][r] = v.y;
            sInT[k4 + 2][r] = v.z; sInT[k4 + 3][r] = v.w;
        }
        {
            const float4* Wv = (const float4*)&W[(size_t)kt * 128];
            float4* sWv = (float4*)&sW[0][0];
            for (int i = t; i < 1024; i += 256) sWv[i] = Wv[i];
        }
        __syncthreads();
#pragma unroll
        for (int k = 0; k < 32; ++k) {
            float4 a = *(const float4*)&sInT[k][tr << 2];
            float4 b = *(const float4*)&sW[k][tc << 2];
            FMA16(a, b, acc)
        }
        __syncthreads();
    }
#pragma unroll
    for (int i = 0; i < 4; ++i) {
        int gr = rbase + (tr << 2) + i;
        if (gr < n) {
            uint2 pk;
            pk.x = pk2(acc[i][0], acc[i][1]);
            pk.y = pk2(acc[i][2], acc[i][3]);
            *(uint2*)((uint32_t*)Out + (size_t)gr * 64 + (tc << 1)) = pk;
        }
    }
}

__global__ __launch_bounds__(256) void gemmA_kernel(const __hip_bfloat16* __restrict__ In,
                                                    const float* __restrict__ W,
                                                    __hip_bfloat16* __restrict__ Out, int n) {
    __shared__ float sInT[32][64];
    __shared__ float sW[32][64];
    int t = threadIdx.x;
    int tr = t >> 4, tc = t & 15;
    int rbase = blockIdx.x * 64;
    float acc[4][4] = {};
    const uint32_t* Inu = (const uint32_t*)In;
    for (int kt = 0; kt < 128; kt += 32) {
        for (int i = t; i < 1024; i += 256) {
            int r = i >> 4, ku = i & 15;
            int gr = rbase + r;
            uint32_t u = (gr < n) ? Inu[(size_t)gr * 64 + (kt >> 1) + ku] : 0u;
            sInT[2 * ku][r] = lo16f(u);
            sInT[2 * ku + 1][r] = hi16f(u);
        }
        {
            const float4* Wv = (const float4*)&W[(size_t)kt * 64];
            float4* sWv = (float4*)&sW[0][0];
            for (int i = t; i < 512; i += 256) sWv[i] = Wv[i];
        }
        __syncthreads();
#pragma unroll
        for (int k = 0; k < 32; ++k) {
            float4 a = *(const float4*)&sInT[k][tr << 2];
            float4 b = *(const float4*)&sW[k][tc << 2];
            FMA16(a, b, acc)
        }
        __syncthreads();
    }
#pragma unroll
    for (int i = 0; i < 4; ++i) {
        int gr = rbase + (tr << 2) + i;
        if (gr < n) {
            uint2 pk;
            pk.x = pk2(acc[i][0], acc[i][1]);
            pk.y = pk2(acc[i][2], acc[i][3]);
            *(uint2*)((uint32_t*)Out + (size_t)gr * 32 + (tc << 1)) = pk;
        }
    }
}

__global__ __launch_bounds__(256) void gemmB_kernel(const float* __restrict__ In,
                                                    const float* __restrict__ W,
                                                    __hip_bfloat16* __restrict__ Out, int n) {
    __shared__ float sInT[32][64];
    __shared__ float sW[32][64];
    int t = threadIdx.x;
    int tr = t >> 4, tc = t & 15;
    int rbase = blockIdx.x * 64;
    float acc[4][4] = {};
    for (int kt = 0; kt < 64; kt += 32) {
        for (int i = t; i < 512; i += 256) {
            int r = i >> 3, k4 = (i & 7) << 2;
            int gr = rbase + r;
            float4 v = make_float4(0.f, 0.f, 0.f, 0.f);
            if (gr < n) v = *(const float4*)&In[(size_t)gr * 64 + kt + k4];
            sInT[k4 + 0][r] = v.x; sInT[k4 + 1][r] = v.y;
            sInT[k4 + 2][r] = v.z; sInT[k4 + 3][r] = v.w;
        }
        {
            const float4* Wv = (const float4*)&W[(size_t)kt * 64];
            float4* sWv = (float4*)&sW[0][0];
            for (int i = t; i < 512; i += 256) sWv[i] = Wv[i];
        }
        __syncthreads();
#pragma unroll
        for (int k = 0; k < 32; ++k) {
            float4 a = *(const float4*)&sInT[k][tr << 2];
            float4 b = *(const float4*)&sW[k][tc << 2];
            FMA16(a, b, acc)
        }
        __syncthreads();
    }
#pragma unroll
    for (int i = 0; i < 4; ++i) {
        int gr = rbase + (tr << 2) + i;
        if (gr < n) {
            uint2 pk;
            pk.x = pk2(acc[i][0], acc[i][1]);
            pk.y = pk2(acc[i][2], acc[i][3]);
            *(uint2*)((uint32_t*)Out + (size_t)gr * 32 + (tc << 1)) = pk;
        }
    }
}

// ---------------- Gathers (one wave per dst row, unroll-4, packed adjacency) ----
__global__ __launch_bounds__(256) void gather128_kernel(
    const __hip_bfloat16* __restrict__ xw, const int* __restrict__ row_ptr,
    const int2* __restrict__ colw, const float* __restrict__ dinv,
    const float* __restrict__ b1, __hip_bfloat16* __restrict__ h1, int n) {
    int w = threadIdx.x >> 6, l = threadIdx.x & 63;
    int d = blockIdx.x * 4 + w;
    if (d >= n) return;
    float dd = dinv[d];
    int p0 = row_ptr[d], p1 = row_ptr[d + 1];
    const uint32_t* X = (const uint32_t*)xw;
    uint32_t v = X[(size_t)d * 64 + l];
    float a0 = dd * lo16f(v), a1 = dd * hi16f(v);
    int e = p0;
    for (; e + 4 <= p1; e += 4) {
        int2 c0 = colw[e], c1 = colw[e + 1], c2 = colw[e + 2], c3 = colw[e + 3];
        uint32_t v0 = X[(size_t)c0.x * 64 + l];
        uint32_t v1 = X[(size_t)c1.x * 64 + l];
        uint32_t v2 = X[(size_t)c2.x * 64 + l];
        uint32_t v3 = X[(size_t)c3.x * 64 + l];
        float w0 = __int_as_float(c0.y), w1 = __int_as_float(c1.y);
        float w2 = __int_as_float(c2.y), w3 = __int_as_float(c3.y);
        a0 = fmaf(w0, lo16f(v0), a0); a1 = fmaf(w0, hi16f(v0), a1);
        a0 = fmaf(w1, lo16f(v1), a0); a1 = fmaf(w1, hi16f(v1), a1);
        a0 = fmaf(w2, lo16f(v2), a0); a1 = fmaf(w2, hi16f(v2), a1);
        a0 = fmaf(w3, lo16f(v3), a0); a1 = fmaf(w3, hi16f(v3), a1);
    }
    for (; e < p1; ++e) {
        int2 c = colw[e];
        uint32_t vv = X[(size_t)c.x * 64 + l];
        float ww = __int_as_float(c.y);
        a0 = fmaf(ww, lo16f(vv), a0); a1 = fmaf(ww, hi16f(vv), a1);
    }
    a0 = fmaxf(fmaf(dd, a0, b1[2 * l]), 0.0f);
    a1 = fmaxf(fmaf(dd, a1, b1[2 * l + 1]), 0.0f);
    ((uint32_t*)h1)[(size_t)d * 64 + l] = pk2(a0, a1);
}

// OUT=0: fp32 out; OUT=1: bf16 out.
template<bool RELU, int OUT>
__global__ __launch_bounds__(256) void gather64b_kernel(
    const __hip_bfloat16* __restrict__ xw, const int* __restrict__ row_ptr,
    const int2* __restrict__ colw, const float* __restrict__ dinv,
    const float* __restrict__ b, void* __restrict__ out, int n) {
    int w = threadIdx.x >> 6, l = threadIdx.x & 63;
    int d = blockIdx.x * 4 + w;
    if (d >= n) return;
    float dd = dinv[d];
    int p0 = row_ptr[d], p1 = row_ptr[d + 1];
    const unsigned short* X = (const unsigned short*)xw;
    float a = dd * u16f(X[(size_t)d * 64 + l]);
    int e = p0;
    for (; e + 4 <= p1; e += 4) {
        int2 c0 = colw[e], c1 = colw[e + 1], c2 = colw[e + 2], c3 = colw[e + 3];
        unsigned short v0 = X[(size_t)c0.x * 64 + l];
        unsigned short v1 = X[(size_t)c1.x * 64 + l];
        unsigned short v2 = X[(size_t)c2.x * 64 + l];
        unsigned short v3 = X[(size_t)c3.x * 64 + l];
        a = fmaf(__int_as_float(c0.y), u16f(v0), a);
        a = fmaf(__int_as_float(c1.y), u16f(v1), a);
        a = fmaf(__int_as_float(c2.y), u16f(v2), a);
        a = fmaf(__int_as_float(c3.y), u16f(v3), a);
    }
    for (; e < p1; ++e) {
        int2 c = colw[e];
        a = fmaf(__int_as_float(c.y), u16f(X[(size_t)c.x * 64 + l]), a);
    }
    float r = fmaf(dd, a, b[l]);
    if (RELU) r = fmaxf(r, 0.0f);
    if (OUT == 0) ((float*)out)[(size_t)d * 64 + l] = r;
    else ((unsigned short*)out)[(size_t)d * 64 + l] = bf16bits(r);
}

// ---------------- Score: 8 edges per wave, 8-lane groups, uint4 row loads ----------
__global__ void score_kernel(const __hip_bfloat16* __restrict__ h, const int* __restrict__ pos,
                             const int* __restrict__ neg, int Ep, int En,
                             float* __restrict__ out) {
    int wid = (int)(((size_t)blockIdx.x * blockDim.x + threadIdx.x) >> 6);
    int lane = threadIdx.x & 63;
    int g = lane >> 3, sl = lane & 7;
    int ed = wid * 8 + g;
    int tot = Ep + En;
    if (ed >= tot) return;
    int j, i;
    if (ed < Ep) { j = pos[ed]; i = pos[Ep + ed]; }
    else { int e = ed - Ep; j = neg[e]; i = neg[En + e]; }
    const uint4* X = (const uint4*)h;  // 8 uint4 per 64-feat bf16 row
    uint4 vi = X[(size_t)i * 8 + sl];
    uint4 vj = X[(size_t)j * 8 + sl];
    float v;
    v = lo16f(vi.x) * lo16f(vj.x);
    v = fmaf(hi16f(vi.x), hi16f(vj.x), v);
    v = fmaf(lo16f(vi.y), lo16f(vj.y), v);
    v = fmaf(hi16f(vi.y), hi16f(vj.y), v);
    v = fmaf(lo16f(vi.z), lo16f(vj.z), v);
    v = fmaf(hi16f(vi.z), hi16f(vj.z), v);
    v = fmaf(lo16f(vi.w), lo16f(vj.w), v);
    v = fmaf(hi16f(vi.w), hi16f(vj.w), v);
#pragma unroll
    for (int o = 4; o > 0; o >>= 1) v += __shfl_xor(v, o);
    if (sl == 0) out[ed] = v;
}

extern "C" void kernel_launch(void* const* d_in, const int* in_sizes, int n_in,
                              void* d_out, int out_size, void* d_ws, size_t ws_size,
                              hipStream_t stream) {
    const float* x   = (const float*)d_in[0];
    const int* train = (const int*)d_in[1];
    const int* pos   = (const int*)d_in[2];
    const int* neg   = (const int*)d_in[3];
    const float* W1  = (const float*)d_in[4];
    const float* b1  = (const float*)d_in[5];
    const float* W2  = (const float*)d_in[6];
    const float* b2  = (const float*)d_in[7];
    const float* W3  = (const float*)d_in[8];
    const float* b3  = (const float*)d_in[9];

    const int n  = in_sizes[0] / 128;
    const int E  = in_sizes[1] / 2;
    const int Ep = in_sizes[2] / 2;
    const int En = in_sizes[3] / 2;

    const int B  = (E + ECH - 1) / ECH;         // partition chunks (391 for E=1.6M)
    const int NB = ((n - 1) >> SHIFT) + 1;      // buckets (391 for n=100K)

    // Workspace (~78 MB)
    char* wp = (char*)d_ws;
    auto alloc = [&](size_t bytes) { char* r = wp; wp += (bytes + 255) & ~(size_t)255; return r; };
    int*   count    = (int*)alloc((size_t)n * 4);
    int*   row_ptr  = (int*)alloc(((size_t)n + 1) * 4);
    int*   partial  = (int*)alloc(256 * 4);
    int*   bucketTotal = (int*)alloc(MAXNB * 4);
    int*   bucketBase  = (int*)alloc(MAXNB * 4);
    int2*  colw     = (int2*)alloc((size_t)E * 8);
    float* dinv     = (float*)alloc((size_t)n * 4);
    __hip_bfloat16* xw1 = (__hip_bfloat16*)alloc((size_t)n * 128 * 2);  // reused as h3(bf16 n*64)
    __hip_bfloat16* h1  = (__hip_bfloat16*)alloc((size_t)n * 128 * 2);
    __hip_bfloat16* P   = (__hip_bfloat16*)alloc((size_t)n * 64 * 2);   // xw2, later xw3
    __hip_bfloat16* h3  = xw1;
    __hip_bfloat16* xw3 = P;
    int2* bedges = (int2*)h1;       // alias: consumed before h1 is written
    int*  histG  = (int*)P;         // alias: NB*B*4 ~ 612KB, consumed before P is written

    float* out_scores = (float*)d_out;
    float* out_embed  = out_scores + (Ep + En);  // h2 lives here directly

    const int eb256 = (E + 255) / 256;
    const int nbs = (n + 1023) / 1024;

    // degrees -> row_ptr, dinv
    hipMemsetAsync(count, 0, (size_t)n * sizeof(int), stream);
    count_kernel<<<eb256, 256, 0, stream>>>(train + E, E, count);
    scan_partial_kernel<<<nbs, 256, 0, stream>>>(count, n, partial);
    scan_offsets_kernel<<<1, 256, 0, stream>>>(partial, nbs, row_ptr, n);
    scan_write_kernel<<<nbs, 256, 0, stream>>>(count, n, partial, row_ptr, dinv);

    // radix-partitioned CSR build (no global atomics, block-local writes)
    part_hist_kernel<<<B, 256, 0, stream>>>(train + E, E, B, NB, histG);
    part_scan_kernel<<<NB, 256, 0, stream>>>(histG, B, bucketTotal);
    bucket_base_kernel<<<1, 256, 0, stream>>>(bucketTotal, NB, bucketBase);
    part_scatter_kernel<<<B, 256, 0, stream>>>(train, train + E, E, B, NB, histG, bucketBase, bedges);
    csr_fill_kernel<<<NB, 256, 0, stream>>>(bedges, bucketBase, bucketTotal, row_ptr, dinv, n, colw);

    // Layer 1
    gemm1_kernel<<<(n + 31) / 32, 256, 0, stream>>>(x, W1, xw1, n);
    gather128_kernel<<<(n + 3) / 4, 256, 0, stream>>>(xw1, row_ptr, colw, dinv, b1, h1, n);
    gemmA_kernel<<<(n + 63) / 64, 256, 0, stream>>>(h1, W2, P, n);

    // Layer 2 (h2 written straight into out_embed, fp32)
    gather64b_kernel<true, 0><<<(n + 3) / 4, 256, 0, stream>>>(
        P, row_ptr, colw, dinv, b2, out_embed, n);

    // Layer 3 (h3 emitted bf16 for the score stage)
    gemmB_kernel<<<(n + 63) / 64, 256, 0, stream>>>(out_embed, W3, xw3, n);
    gather64b_kernel<false, 1><<<(n + 3) / 4, 256, 0, stream>>>(
        xw3, row_ptr, colw, dinv, b3, h3, n);

    // Scores: 8 edges per wave
    {
        int waves = (Ep + En + 7) / 8;
        score_kernel<<<(int)(((size_t)waves * 64 + 255) / 256), 256, 0, stream>>>(
            h3, pos, neg, Ep, En, out_scores);
    }
}

// Round 12
// 441.584 us; speedup vs baseline: 1.3230x; 1.0566x over previous
//
#include <hip/hip_runtime.h>
#include <hip/hip_bf16.h>

// GCN link prediction. Inputs fp32+int32; OUTPUT fp32 (scores[1M] ++ embed[n*64]).
// CSR gather + bf16 feature tables (fp32 math), register-tiled 4x4 GEMMs,
// device-wide scan, radix-partitioned CSR build, 8-edge/wave uint4 score,
// unroll-8 dual-accumulator gathers (latency-bound: VALU 37%, HBM 37%).

#define ECH 4096      // edges per partition chunk
#define SHIFT 8       // dsts per bucket = 256
#define MAXNB 512     // max buckets (n <= 131072)

__device__ __forceinline__ float lo16f(uint32_t u) { uint32_t x = u << 16; float f; __builtin_memcpy(&f, &x, 4); return f; }
__device__ __forceinline__ float hi16f(uint32_t u) { uint32_t x = u & 0xffff0000u; float f; __builtin_memcpy(&f, &x, 4); return f; }
__device__ __forceinline__ float u16f(unsigned short u) { uint32_t x = (uint32_t)u << 16; float f; __builtin_memcpy(&f, &x, 4); return f; }
__device__ __forceinline__ uint32_t pk2(float a, float b) {
    union { __hip_bfloat162 h; uint32_t u; } cv;
    cv.h = __hip_bfloat162(__float2bfloat16(a), __float2bfloat16(b));
    return cv.u;
}
__device__ __forceinline__ unsigned short bf16bits(float a) {
    union { __hip_bfloat16 b; unsigned short u; } cv;
    cv.b = __float2bfloat16(a);
    return cv.u;
}

// ---------------- degree count + row_ptr scan ----------------
__global__ void count_kernel(const int* __restrict__ dst, int E, int* __restrict__ count) {
    int e = blockIdx.x * blockDim.x + threadIdx.x;
    if (e < E) atomicAdd(&count[dst[e]], 1);
}

__global__ __launch_bounds__(256) void scan_partial_kernel(const int* __restrict__ count, int n,
                                                           int* __restrict__ partial) {
    __shared__ int red[256];
    int t = threadIdx.x;
    int base = blockIdx.x * 1024 + t * 4;
    int s = 0;
#pragma unroll
    for (int i = 0; i < 4; ++i) {
        int idx = base + i;
        if (idx < n) s += count[idx];
    }
    red[t] = s;
    __syncthreads();
    for (int o = 128; o > 0; o >>= 1) {
        if (t < o) red[t] += red[t + o];
        __syncthreads();
    }
    if (t == 0) partial[blockIdx.x] = red[0];
}

__global__ __launch_bounds__(256) void scan_offsets_kernel(int* __restrict__ partial, int nb,
                                                           int* __restrict__ row_ptr, int n) {
    __shared__ int sc[256];
    int t = threadIdx.x;
    sc[t] = (t < nb) ? partial[t] : 0;
    __syncthreads();
    for (int o = 1; o < 256; o <<= 1) {
        int v = sc[t];
        int u = (t >= o) ? sc[t - o] : 0;
        __syncthreads();
        sc[t] = v + u;
        __syncthreads();
    }
    if (t < nb) partial[t] = (t > 0) ? sc[t - 1] : 0;  // exclusive
    if (t == 0) row_ptr[n] = sc[255];
}

__global__ __launch_bounds__(256) void scan_write_kernel(const int* __restrict__ count, int n,
                                                         const int* __restrict__ partial,
                                                         int* __restrict__ row_ptr,
                                                         float* __restrict__ dinv) {
    __shared__ int sc[256];
    int t = threadIdx.x;
    int base = blockIdx.x * 1024 + t * 4;
    int c[4];
    int s = 0;
#pragma unroll
    for (int i = 0; i < 4; ++i) {
        int idx = base + i;
        c[i] = (idx < n) ? count[idx] : 0;
        s += c[i];
    }
    sc[t] = s;
    __syncthreads();
    for (int o = 1; o < 256; o <<= 1) {
        int v = sc[t];
        int u = (t >= o) ? sc[t - o] : 0;
        __syncthreads();
        sc[t] = v + u;
        __syncthreads();
    }
    int run = partial[blockIdx.x] + ((t > 0) ? sc[t - 1] : 0);
#pragma unroll
    for (int i = 0; i < 4; ++i) {
        int idx = base + i;
        if (idx < n) {
            row_ptr[idx] = run;
            dinv[idx] = rsqrtf((float)c[i] + 1.0f);
            run += c[i];
        }
    }
}

// ---------------- radix partition: edges -> buckets -> CSR ----------------
__global__ __launch_bounds__(256) void part_hist_kernel(const int* __restrict__ dst, int E,
                                                        int B, int NB, int* __restrict__ histG) {
    __shared__ int h[MAXNB];
    int t = threadIdx.x, blk = blockIdx.x;
    for (int i = t; i < NB; i += 256) h[i] = 0;
    __syncthreads();
    int lo = blk * ECH, hi = min(lo + ECH, E);
    for (int i = lo + t; i < hi; i += 256) atomicAdd(&h[dst[i] >> SHIFT], 1);
    __syncthreads();
    for (int k = t; k < NB; k += 256) histG[(size_t)k * B + blk] = h[k];
}

__global__ __launch_bounds__(256) void part_scan_kernel(int* __restrict__ histG, int B,
                                                        int* __restrict__ bucketTotal) {
    __shared__ int sc[1024];   // supports B <= 1024
    int k = blockIdx.x, t = threadIdx.x;
    for (int i = t; i < 1024; i += 256) sc[i] = (i < B) ? histG[(size_t)k * B + i] : 0;
    __syncthreads();
    for (int o = 1; o < 1024; o <<= 1) {
        int v[4];
#pragma unroll
        for (int j = 0; j < 4; ++j) { int i = t + j * 256; v[j] = (i >= o) ? sc[i - o] : 0; }
        __syncthreads();
#pragma unroll
        for (int j = 0; j < 4; ++j) sc[t + j * 256] += v[j];
        __syncthreads();
    }
    for (int i = t; i < B; i += 256) histG[(size_t)k * B + i] = (i > 0) ? sc[i - 1] : 0;
    if (t == 0) bucketTotal[k] = sc[B - 1];
}

__global__ __launch_bounds__(256) void bucket_base_kernel(const int* __restrict__ bucketTotal,
                                                          int NB, int* __restrict__ bucketBase) {
    __shared__ int sc[MAXNB];
    int t = threadIdx.x;
    for (int i = t; i < MAXNB; i += 256) sc[i] = (i < NB) ? bucketTotal[i] : 0;
    __syncthreads();
    for (int o = 1; o < MAXNB; o <<= 1) {
        int v[MAXNB / 256];
#pragma unroll
        for (int j = 0; j < MAXNB / 256; ++j) { int i = t + j * 256; v[j] = (i >= o) ? sc[i - o] : 0; }
        __syncthreads();
#pragma unroll
        for (int j = 0; j < MAXNB / 256; ++j) sc[t + j * 256] += v[j];
        __syncthreads();
    }
    for (int i = t; i < NB; i += 256) bucketBase[i] = (i > 0) ? sc[i - 1] : 0;
}

__global__ __launch_bounds__(256) void part_scatter_kernel(
    const int* __restrict__ src, const int* __restrict__ dst, int E, int B, int NB,
    const int* __restrict__ histG, const int* __restrict__ bucketBase,
    int2* __restrict__ bedges) {
    __shared__ int cur[MAXNB];
    int t = threadIdx.x, blk = blockIdx.x;
    for (int k = t; k < NB; k += 256) cur[k] = bucketBase[k] + histG[(size_t)k * B + blk];
    __syncthreads();
    int lo = blk * ECH, hi = min(lo + ECH, E);
    for (int i = lo + t; i < hi; i += 256) {
        int s = src[i], d = dst[i];
        int p = atomicAdd(&cur[d >> SHIFT], 1);
        bedges[p] = make_int2(s, d);
    }
}

__global__ __launch_bounds__(256) void csr_fill_kernel(
    const int2* __restrict__ bedges, const int* __restrict__ bucketBase,
    const int* __restrict__ bucketTotal, const int* __restrict__ row_ptr,
    const float* __restrict__ dinv, int n, int2* __restrict__ colw) {
    __shared__ int cur[1 << SHIFT];
    int k = blockIdx.x, t = threadIdx.x;
    int d0 = k << SHIFT;
    for (int i = t; i < (1 << SHIFT); i += 256) {
        int d = d0 + i;
        cur[i] = (d < n) ? row_ptr[d] : 0;
    }
    __syncthreads();
    int base = bucketBase[k], cnt = bucketTotal[k];
    for (int i = t; i < cnt; i += 256) {
        int2 e = bedges[base + i];
        float w = dinv[e.x];
        int p = atomicAdd(&cur[e.y - d0], 1);
        colw[p] = make_int2(e.x, __float_as_int(w));
    }
}

// ---------------- GEMMs (4x4 register tile, K-chunked LDS) ----------------
#define FMA16(a, b, acc)                                                     \
    acc[0][0] = fmaf(a.x, b.x, acc[0][0]); acc[0][1] = fmaf(a.x, b.y, acc[0][1]); \
    acc[0][2] = fmaf(a.x, b.z, acc[0][2]); acc[0][3] = fmaf(a.x, b.w, acc[0][3]); \
    acc[1][0] = fmaf(a.y, b.x, acc[1][0]); acc[1][1] = fmaf(a.y, b.y, acc[1][1]); \
    acc[1][2] = fmaf(a.y, b.z, acc[1][2]); acc[1][3] = fmaf(a.y, b.w, acc[1][3]); \
    acc[2][0] = fmaf(a.z, b.x, acc[2][0]); acc[2][1] = fmaf(a.z, b.y, acc[2][1]); \
    acc[2][2] = fmaf(a.z, b.z, acc[2][2]); acc[2][3] = fmaf(a.z, b.w, acc[2][3]); \
    acc[3][0] = fmaf(a.w, b.x, acc[3][0]); acc[3][1] = fmaf(a.w, b.y, acc[3][1]); \
    acc[3][2] = fmaf(a.w, b.z, acc[3][2]); acc[3][3] = fmaf(a.w, b.w, acc[3][3]);

__global__ __launch_bounds__(256) void gemm1_kernel(const float* __restrict__ In,
                                                    const float* __restrict__ W,
                                                    __hip_bfloat16* __restrict__ Out, int n) {
    __shared__ float sInT[32][32];   // [k][row]
    __shared__ float sW[32][128];
    int t = threadIdx.x;
    int tr = t >> 5, tc = t & 31;
    int rbase = blockIdx.x * 32;
    float acc[4][4] = {};
    for (int kt = 0; kt < 128; kt += 32) {
        {
            int r = t >> 3, k4 = (t & 7) << 2;
            int gr = rbase + r;
            float4 v = make_float4(0.f, 0.f, 0.f, 0.f);
            if (gr < n) v = *(const float4*)&In[(size_t)gr * 128 + kt + k4];
            sInT[k4 + 0][r] = v.x; sInT[k4 + 1][r] = v.y;
            sInT[k4 + 2][r] = v.z; sInT[k4 + 3][r] = v.w;
        }
        {
            const float4* Wv = (const float4*)&W[(size_t)kt * 128];
            float4* sWv = (float4*)&sW[0][0];
            for (int i = t; i < 1024; i += 256) sWv[i] = Wv[i];
        }
        __syncthreads();
#pragma unroll
        for (int k = 0; k < 32; ++k) {
            float4 a = *(const float4*)&sInT[k][tr << 2];
            float4 b = *(const float4*)&sW[k][tc << 2];
            FMA16(a, b, acc)
        }
        __syncthreads();
    }
#pragma unroll
    for (int i = 0; i < 4; ++i) {
        int gr = rbase + (tr << 2) + i;
        if (gr < n) {
            uint2 pk;
            pk.x = pk2(acc[i][0], acc[i][1]);
            pk.y = pk2(acc[i][2], acc[i][3]);
            *(uint2*)((uint32_t*)Out + (size_t)gr * 64 + (tc << 1)) = pk;
        }
    }
}

__global__ __launch_bounds__(256) void gemmA_kernel(const __hip_bfloat16* __restrict__ In,
                                                    const float* __restrict__ W,
                                                    __hip_bfloat16* __restrict__ Out, int n) {
    __shared__ float sInT[32][64];
    __shared__ float sW[32][64];
    int t = threadIdx.x;
    int tr = t >> 4, tc = t & 15;
    int rbase = blockIdx.x * 64;
    float acc[4][4] = {};
    const uint32_t* Inu = (const uint32_t*)In;
    for (int kt = 0; kt < 128; kt += 32) {
        for (int i = t; i < 1024; i += 256) {
            int r = i >> 4, ku = i & 15;
            int gr = rbase + r;
            uint32_t u = (gr < n) ? Inu[(size_t)gr * 64 + (kt >> 1) + ku] : 0u;
            sInT[2 * ku][r] = lo16f(u);
            sInT[2 * ku + 1][r] = hi16f(u);
        }
        {
            const float4* Wv = (const float4*)&W[(size_t)kt * 64];
            float4* sWv = (float4*)&sW[0][0];
            for (int i = t; i < 512; i += 256) sWv[i] = Wv[i];
        }
        __syncthreads();
#pragma unroll
        for (int k = 0; k < 32; ++k) {
            float4 a = *(const float4*)&sInT[k][tr << 2];
            float4 b = *(const float4*)&sW[k][tc << 2];
            FMA16(a, b, acc)
        }
        __syncthreads();
    }
#pragma unroll
    for (int i = 0; i < 4; ++i) {
        int gr = rbase + (tr << 2) + i;
        if (gr < n) {
            uint2 pk;
            pk.x = pk2(acc[i][0], acc[i][1]);
            pk.y = pk2(acc[i][2], acc[i][3]);
            *(uint2*)((uint32_t*)Out + (size_t)gr * 32 + (tc << 1)) = pk;
        }
    }
}

__global__ __launch_bounds__(256) void gemmB_kernel(const float* __restrict__ In,
                                                    const float* __restrict__ W,
                                                    __hip_bfloat16* __restrict__ Out, int n) {
    __shared__ float sInT[32][64];
    __shared__ float sW[32][64];
    int t = threadIdx.x;
    int tr = t >> 4, tc = t & 15;
    int rbase = blockIdx.x * 64;
    float acc[4][4] = {};
    for (int kt = 0; kt < 64; kt += 32) {
        for (int i = t; i < 512; i += 256) {
            int r = i >> 3, k4 = (i & 7) << 2;
            int gr = rbase + r;
            float4 v = make_float4(0.f, 0.f, 0.f, 0.f);
            if (gr < n) v = *(const float4*)&In[(size_t)gr * 64 + kt + k4];
            sInT[k4 + 0][r] = v.x; sInT[k4 + 1][r] = v.y;
            sInT[k4 + 2][r] = v.z; sInT[k4 + 3][r] = v.w;
        }
        {
            const float4* Wv = (const float4*)&W[(size_t)kt * 64];
            float4* sWv = (float4*)&sW[0][0];
            for (int i = t; i < 512; i += 256) sWv[i] = Wv[i];
        }
        __syncthreads();
#pragma unroll
        for (int k = 0; k < 32; ++k) {
            float4 a = *(const float4*)&sInT[k][tr << 2];
            float4 b = *(const float4*)&sW[k][tc << 2];
            FMA16(a, b, acc)
        }
        __syncthreads();
    }
#pragma unroll
    for (int i = 0; i < 4; ++i) {
        int gr = rbase + (tr << 2) + i;
        if (gr < n) {
            uint2 pk;
            pk.x = pk2(acc[i][0], acc[i][1]);
            pk.y = pk2(acc[i][2], acc[i][3]);
            *(uint2*)((uint32_t*)Out + (size_t)gr * 32 + (tc << 1)) = pk;
        }
    }
}

// ---------------- Gathers (one wave per dst row, unroll-8, dual accumulators) ----
__global__ __launch_bounds__(256) void gather128_kernel(
    const __hip_bfloat16* __restrict__ xw, const int* __restrict__ row_ptr,
    const int2* __restrict__ colw, const float* __restrict__ dinv,
    const float* __restrict__ b1, __hip_bfloat16* __restrict__ h1, int n) {
    int w = threadIdx.x >> 6, l = threadIdx.x & 63;
    int d = blockIdx.x * 4 + w;
    if (d >= n) return;
    float dd = dinv[d];
    int p0 = row_ptr[d], p1 = row_ptr[d + 1];
    const uint32_t* X = (const uint32_t*)xw;
    uint32_t v = X[(size_t)d * 64 + l];
    float a0 = dd * lo16f(v), a1 = dd * hi16f(v);
    float c0a = 0.f, c1a = 0.f;   // second accumulator pair (chain break)
    int e = p0;
    for (; e + 8 <= p1; e += 8) {
        int2 q0 = colw[e], q1 = colw[e + 1], q2 = colw[e + 2], q3 = colw[e + 3];
        int2 q4 = colw[e + 4], q5 = colw[e + 5], q6 = colw[e + 6], q7 = colw[e + 7];
        uint32_t v0 = X[(size_t)q0.x * 64 + l];
        uint32_t v1 = X[(size_t)q1.x * 64 + l];
        uint32_t v2 = X[(size_t)q2.x * 64 + l];
        uint32_t v3 = X[(size_t)q3.x * 64 + l];
        uint32_t v4 = X[(size_t)q4.x * 64 + l];
        uint32_t v5 = X[(size_t)q5.x * 64 + l];
        uint32_t v6 = X[(size_t)q6.x * 64 + l];
        uint32_t v7 = X[(size_t)q7.x * 64 + l];
        float w0 = __int_as_float(q0.y), w1 = __int_as_float(q1.y);
        float w2 = __int_as_float(q2.y), w3 = __int_as_float(q3.y);
        float w4 = __int_as_float(q4.y), w5 = __int_as_float(q5.y);
        float w6 = __int_as_float(q6.y), w7 = __int_as_float(q7.y);
        a0 = fmaf(w0, lo16f(v0), a0);  a1 = fmaf(w0, hi16f(v0), a1);
        c0a = fmaf(w1, lo16f(v1), c0a); c1a = fmaf(w1, hi16f(v1), c1a);
        a0 = fmaf(w2, lo16f(v2), a0);  a1 = fmaf(w2, hi16f(v2), a1);
        c0a = fmaf(w3, lo16f(v3), c0a); c1a = fmaf(w3, hi16f(v3), c1a);
        a0 = fmaf(w4, lo16f(v4), a0);  a1 = fmaf(w4, hi16f(v4), a1);
        c0a = fmaf(w5, lo16f(v5), c0a); c1a = fmaf(w5, hi16f(v5), c1a);
        a0 = fmaf(w6, lo16f(v6), a0);  a1 = fmaf(w6, hi16f(v6), a1);
        c0a = fmaf(w7, lo16f(v7), c0a); c1a = fmaf(w7, hi16f(v7), c1a);
    }
    for (; e + 4 <= p1; e += 4) {
        int2 q0 = colw[e], q1 = colw[e + 1], q2 = colw[e + 2], q3 = colw[e + 3];
        uint32_t v0 = X[(size_t)q0.x * 64 + l];
        uint32_t v1 = X[(size_t)q1.x * 64 + l];
        uint32_t v2 = X[(size_t)q2.x * 64 + l];
        uint32_t v3 = X[(size_t)q3.x * 64 + l];
        float w0 = __int_as_float(q0.y), w1 = __int_as_float(q1.y);
        float w2 = __int_as_float(q2.y), w3 = __int_as_float(q3.y);
        a0 = fmaf(w0, lo16f(v0), a0);  a1 = fmaf(w0, hi16f(v0), a1);
        c0a = fmaf(w1, lo16f(v1), c0a); c1a = fmaf(w1, hi16f(v1), c1a);
        a0 = fmaf(w2, lo16f(v2), a0);  a1 = fmaf(w2, hi16f(v2), a1);
        c0a = fmaf(w3, lo16f(v3), c0a); c1a = fmaf(w3, hi16f(v3), c1a);
    }
    for (; e < p1; ++e) {
        int2 c = colw[e];
        uint32_t vv = X[(size_t)c.x * 64 + l];
        float ww = __int_as_float(c.y);
        a0 = fmaf(ww, lo16f(vv), a0); a1 = fmaf(ww, hi16f(vv), a1);
    }
    a0 += c0a; a1 += c1a;
    a0 = fmaxf(fmaf(dd, a0, b1[2 * l]), 0.0f);
    a1 = fmaxf(fmaf(dd, a1, b1[2 * l + 1]), 0.0f);
    ((uint32_t*)h1)[(size_t)d * 64 + l] = pk2(a0, a1);
}

// OUT=0: fp32 out; OUT=1: bf16 out.
template<bool RELU, int OUT>
__global__ __launch_bounds__(256) void gather64b_kernel(
    const __hip_bfloat16* __restrict__ xw, const int* __restrict__ row_ptr,
    const int2* __restrict__ colw, const float* __restrict__ dinv,
    const float* __restrict__ b, void* __restrict__ out, int n) {
    int w = threadIdx.x >> 6, l = threadIdx.x & 63;
    int d = blockIdx.x * 4 + w;
    if (d >= n) return;
    float dd = dinv[d];
    int p0 = row_ptr[d], p1 = row_ptr[d + 1];
    const unsigned short* X = (const unsigned short*)xw;
    float a = dd * u16f(X[(size_t)d * 64 + l]);
    float c = 0.f;   // second accumulator (chain break)
    int e = p0;
    for (; e + 8 <= p1; e += 8) {
        int2 q0 = colw[e], q1 = colw[e + 1], q2 = colw[e + 2], q3 = colw[e + 3];
        int2 q4 = colw[e + 4], q5 = colw[e + 5], q6 = colw[e + 6], q7 = colw[e + 7];
        unsigned short v0 = X[(size_t)q0.x * 64 + l];
        unsigned short v1 = X[(size_t)q1.x * 64 + l];
        unsigned short v2 = X[(size_t)q2.x * 64 + l];
        unsigned short v3 = X[(size_t)q3.x * 64 + l];
        unsigned short v4 = X[(size_t)q4.x * 64 + l];
        unsigned short v5 = X[(size_t)q5.x * 64 + l];
        unsigned short v6 = X[(size_t)q6.x * 64 + l];
        unsigned short v7 = X[(size_t)q7.x * 64 + l];
        a = fmaf(__int_as_float(q0.y), u16f(v0), a);
        c = fmaf(__int_as_float(q1.y), u16f(v1), c);
        a = fmaf(__int_as_float(q2.y), u16f(v2), a);
        c = fmaf(__int_as_float(q3.y), u16f(v3), c);
        a = fmaf(__int_as_float(q4.y), u16f(v4), a);
        c = fmaf(__int_as_float(q5.y), u16f(v5), c);
        a = fmaf(__int_as_float(q6.y), u16f(v6), a);
        c = fmaf(__int_as_float(q7.y), u16f(v7), c);
    }
    for (; e + 4 <= p1; e += 4) {
        int2 q0 = colw[e], q1 = colw[e + 1], q2 = colw[e + 2], q3 = colw[e + 3];
        unsigned short v0 = X[(size_t)q0.x * 64 + l];
        unsigned short v1 = X[(size_t)q1.x * 64 + l];
        unsigned short v2 = X[(size_t)q2.x * 64 + l];
        unsigned short v3 = X[(size_t)q3.x * 64 + l];
        a = fmaf(__int_as_float(q0.y), u16f(v0), a);
        c = fmaf(__int_as_float(q1.y), u16f(v1), c);
        a = fmaf(__int_as_float(q2.y), u16f(v2), a);
        c = fmaf(__int_as_float(q3.y), u16f(v3), c);
    }
    for (; e < p1; ++e) {
        int2 q = colw[e];
        a = fmaf(__int_as_float(q.y), u16f(X[(size_t)q.x * 64 + l]), a);
    }
    a += c;
    float r = fmaf(dd, a, b[l]);
    if (RELU) r = fmaxf(r, 0.0f);
    if (OUT == 0) ((float*)out)[(size_t)d * 64 + l] = r;
    else ((unsigned short*)out)[(size_t)d * 64 + l] = bf16bits(r);
}

// ---------------- Score: 8 edges per wave, 8-lane groups, uint4 row loads ----------
__global__ void score_kernel(const __hip_bfloat16* __restrict__ h, const int* __restrict__ pos,
                             const int* __restrict__ neg, int Ep, int En,
                             float* __restrict__ out) {
    int wid = (int)(((size_t)blockIdx.x * blockDim.x + threadIdx.x) >> 6);
    int lane = threadIdx.x & 63;
    int g = lane >> 3, sl = lane & 7;
    int ed = wid * 8 + g;
    int tot = Ep + En;
    if (ed >= tot) return;
    int j, i;
    if (ed < Ep) { j = pos[ed]; i = pos[Ep + ed]; }
    else { int e = ed - Ep; j = neg[e]; i = neg[En + e]; }
    const uint4* X = (const uint4*)h;  // 8 uint4 per 64-feat bf16 row
    uint4 vi = X[(size_t)i * 8 + sl];
    uint4 vj = X[(size_t)j * 8 + sl];
    float v;
    v = lo16f(vi.x) * lo16f(vj.x);
    v = fmaf(hi16f(vi.x), hi16f(vj.x), v);
    v = fmaf(lo16f(vi.y), lo16f(vj.y), v);
    v = fmaf(hi16f(vi.y), hi16f(vj.y), v);
    v = fmaf(lo16f(vi.z), lo16f(vj.z), v);
    v = fmaf(hi16f(vi.z), hi16f(vj.z), v);
    v = fmaf(lo16f(vi.w), lo16f(vj.w), v);
    v = fmaf(hi16f(vi.w), hi16f(vj.w), v);
#pragma unroll
    for (int o = 4; o > 0; o >>= 1) v += __shfl_xor(v, o);
    if (sl == 0) out[ed] = v;
}

extern "C" void kernel_launch(void* const* d_in, const int* in_sizes, int n_in,
                              void* d_out, int out_size, void* d_ws, size_t ws_size,
                              hipStream_t stream) {
    const float* x   = (const float*)d_in[0];
    const int* train = (const int*)d_in[1];
    const int* pos   = (const int*)d_in[2];
    const int* neg   = (const int*)d_in[3];
    const float* W1  = (const float*)d_in[4];
    const float* b1  = (const float*)d_in[5];
    const float* W2  = (const float*)d_in[6];
    const float* b2  = (const float*)d_in[7];
    const float* W3  = (const float*)d_in[8];
    const float* b3  = (const float*)d_in[9];

    const int n  = in_sizes[0] / 128;
    const int E  = in_sizes[1] / 2;
    const int Ep = in_sizes[2] / 2;
    const int En = in_sizes[3] / 2;

    const int B  = (E + ECH - 1) / ECH;         // partition chunks (391 for E=1.6M)
    const int NB = ((n - 1) >> SHIFT) + 1;      // buckets (391 for n=100K)

    // Workspace (~78 MB)
    char* wp = (char*)d_ws;
    auto alloc = [&](size_t bytes) { char* r = wp; wp += (bytes + 255) & ~(size_t)255; return r; };
    int*   count    = (int*)alloc((size_t)n * 4);
    int*   row_ptr  = (int*)alloc(((size_t)n + 1) * 4);
    int*   partial  = (int*)alloc(256 * 4);
    int*   bucketTotal = (int*)alloc(MAXNB * 4);
    int*   bucketBase  = (int*)alloc(MAXNB * 4);
    int2*  colw     = (int2*)alloc((size_t)E * 8);
    float* dinv     = (float*)alloc((size_t)n * 4);
    __hip_bfloat16* xw1 = (__hip_bfloat16*)alloc((size_t)n * 128 * 2);  // reused as h3(bf16 n*64)
    __hip_bfloat16* h1  = (__hip_bfloat16*)alloc((size_t)n * 128 * 2);
    __hip_bfloat16* P   = (__hip_bfloat16*)alloc((size_t)n * 64 * 2);   // xw2, later xw3
    __hip_bfloat16* h3  = xw1;
    __hip_bfloat16* xw3 = P;
    int2* bedges = (int2*)h1;       // alias: consumed before h1 is written
    int*  histG  = (int*)P;         // alias: NB*B*4 ~ 612KB, consumed before P is written

    float* out_scores = (float*)d_out;
    float* out_embed  = out_scores + (Ep + En);  // h2 lives here directly

    const int eb256 = (E + 255) / 256;
    const int nbs = (n + 1023) / 1024;

    // degrees -> row_ptr, dinv
    hipMemsetAsync(count, 0, (size_t)n * sizeof(int), stream);
    count_kernel<<<eb256, 256, 0, stream>>>(train + E, E, count);
    scan_partial_kernel<<<nbs, 256, 0, stream>>>(count, n, partial);
    scan_offsets_kernel<<<1, 256, 0, stream>>>(partial, nbs, row_ptr, n);
    scan_write_kernel<<<nbs, 256, 0, stream>>>(count, n, partial, row_ptr, dinv);

    // radix-partitioned CSR build (no global atomics, block-local writes)
    part_hist_kernel<<<B, 256, 0, stream>>>(train + E, E, B, NB, histG);
    part_scan_kernel<<<NB, 256, 0, stream>>>(histG, B, bucketTotal);
    bucket_base_kernel<<<1, 256, 0, stream>>>(bucketTotal, NB, bucketBase);
    part_scatter_kernel<<<B, 256, 0, stream>>>(train, train + E, E, B, NB, histG, bucketBase, bedges);
    csr_fill_kernel<<<NB, 256, 0, stream>>>(bedges, bucketBase, bucketTotal, row_ptr, dinv, n, colw);

    // Layer 1
    gemm1_kernel<<<(n + 31) / 32, 256, 0, stream>>>(x, W1, xw1, n);
    gather128_kernel<<<(n + 3) / 4, 256, 0, stream>>>(xw1, row_ptr, colw, dinv, b1, h1, n);
    gemmA_kernel<<<(n + 63) / 64, 256, 0, stream>>>(h1, W2, P, n);

    // Layer 2 (h2 written straight into out_embed, fp32)
    gather64b_kernel<true, 0><<<(n + 3) / 4, 256, 0, stream>>>(
        P, row_ptr, colw, dinv, b2, out_embed, n);

    // Layer 3 (h3 emitted bf16 for the score stage)
    gemmB_kernel<<<(n + 63) / 64, 256, 0, stream>>>(out_embed, W3, xw3, n);
    gather64b_kernel<false, 1><<<(n + 3) / 4, 256, 0, stream>>>(
        xw3, row_ptr, colw, dinv, b3, h3, n);

    // Scores: 8 edges per wave
    {
        int waves = (Ep + En + 7) / 8;
        score_kernel<<<(int)(((size_t)waves * 64 + 255) / 256), 256, 0, stream>>>(
            h3, pos, neg, Ep, En, out_scores);
    }
}